// Round 1
// baseline (414.822 us; speedup 1.0000x reference)
//
#include <hip/hip_runtime.h>
#include <math.h>

#define B 64
#define H 1024
#define SEQ 256
#define V 50257

typedef float4 f4;

__device__ inline float sigm(float x){ return 1.0f/(1.0f+expf(-x)); }
__device__ inline float wrsum(float v){
  #pragma unroll
  for(int o=32;o;o>>=1) v += __shfl_xor(v,o);
  return v;
}
__device__ inline float wrmax(float v){
  #pragma unroll
  for(int o=32;o;o>>=1) v = fmaxf(v,__shfl_xor(v,o));
  return v;
}

// Build X[:, :3H] = [lw | h_sum | ctx] and emo. X row stride 4096.
__global__ void k_build(const int* __restrict__ istep, const int* __restrict__ iemo,
                        const float* __restrict__ lasth, const float* __restrict__ ictx,
                        const float* __restrict__ emb, const float* __restrict__ eemb,
                        float* __restrict__ X, float* __restrict__ emo){
  int b = blockIdx.x; int h = threadIdx.x*4;
  int iw = istep[b]; int ie = iemo[b];
  f4 lw = *(const f4*)(emb  + (size_t)iw*H + h);
  f4 hs = *(const f4*)(lasth + (size_t)b*H + h);
  f4 cv = *(const f4*)(ictx + (size_t)b*H + h);
  f4 ev = *(const f4*)(eemb + (size_t)ie*H + h);
  *(f4*)(X + (size_t)b*4096 +        h) = lw;
  *(f4*)(X + (size_t)b*4096 + 1024 + h) = hs;
  *(f4*)(X + (size_t)b*4096 + 2048 + h) = cv;
  *(f4*)(emo + (size_t)b*H + h) = ev;
}

// Skinny GEMM: out[b,n] = sum_k A[b,k]*W[n,k]   (M=64 rows always)
// grid = (ceil(N/64), ksplit); each block does K-range [blockIdx.y*kchunk, +kchunk)
// DIRECT: apply bias, store to out[b*out_ld+n]. else: store partial [ks][64][N].
template<bool DIRECT>
__launch_bounds__(256)
__global__ void k_gemm(const float* __restrict__ A, int lda,
                       const float* __restrict__ Wm, int K, int N, int kchunk,
                       const float* __restrict__ bias,
                       float* __restrict__ out, int out_ld){
  __shared__ float At[64][68];
  __shared__ float Wt[64][68];
  int tid = threadIdx.x;
  int n0 = blockIdx.x*64;
  int kbeg = blockIdx.y*kchunk;
  int q = tid>>6, lane = tid&63;          // A staging
  int wr = tid>>4, wk = tid&15;           // W staging
  int r0 = (tid>>4)*4, c0 = (tid&15)*4;   // compute micro-tile
  float acc[4][4] = {};

  for(int k0 = kbeg; k0 < kbeg+kchunk; k0 += 64){
    // stage A (64 rows x 64 k), transposed into At[k][b]
    {
      const float* ap = A + (size_t)lane*lda + k0 + q*16;
      #pragma unroll
      for(int j=0;j<4;j++){
        f4 v = *(const f4*)(ap + j*4);
        int kl = q*16 + j*4;
        At[kl+0][lane]=v.x; At[kl+1][lane]=v.y; At[kl+2][lane]=v.z; At[kl+3][lane]=v.w;
      }
    }
    // stage W (64 cols x 64 k), transposed into Wt[k][n]; coalesced 256B/row-chunk
    {
      #pragma unroll
      for(int p=0;p<4;p++){
        int n = p*16 + wr;
        int nn = n0 + n; if(nn > N-1) nn = N-1;
        f4 v = *(const f4*)(Wm + (size_t)nn*K + k0 + wk*4);
        int kl = wk*4;
        Wt[kl+0][n]=v.x; Wt[kl+1][n]=v.y; Wt[kl+2][n]=v.z; Wt[kl+3][n]=v.w;
      }
    }
    __syncthreads();
    #pragma unroll 8
    for(int kk=0;kk<64;kk++){
      f4 a = *(const f4*)&At[kk][r0];
      f4 w = *(const f4*)&Wt[kk][c0];
      acc[0][0] += a.x*w.x; acc[0][1] += a.x*w.y; acc[0][2] += a.x*w.z; acc[0][3] += a.x*w.w;
      acc[1][0] += a.y*w.x; acc[1][1] += a.y*w.y; acc[1][2] += a.y*w.z; acc[1][3] += a.y*w.w;
      acc[2][0] += a.z*w.x; acc[2][1] += a.z*w.y; acc[2][2] += a.z*w.z; acc[2][3] += a.z*w.w;
      acc[3][0] += a.w*w.x; acc[3][1] += a.w*w.y; acc[3][2] += a.w*w.z; acc[3][3] += a.w*w.w;
    }
    __syncthreads();
  }

  if(DIRECT){
    #pragma unroll
    for(int i=0;i<4;i++){
      int b = r0+i;
      #pragma unroll
      for(int j=0;j<4;j++){
        int n = n0 + c0 + j;
        if(n < N) out[(size_t)b*out_ld + n] = acc[i][j] + bias[n];
      }
    }
  } else {
    float* pp = out + ((size_t)blockIdx.y*64)*N;
    #pragma unroll
    for(int i=0;i<4;i++){
      #pragma unroll
      for(int j=0;j<4;j++){
        int n = n0 + c0 + j;
        if(n < N) pp[(size_t)(r0+i)*N + n] = acc[i][j];
      }
    }
  }
}

// reduce split-K partials + bias + activation (+ optional elementwise multiplier)
// grid = (N/256, 64)
template<int ACT> // 0 none, 1 sigmoid, 2 tanh
__global__ void k_reduce(const float* __restrict__ part, int ksplit, int N,
                         const float* __restrict__ bias,
                         const float* __restrict__ mul, int mul_ld,
                         float* __restrict__ out, int out_ld){
  int n = blockIdx.x*256 + threadIdx.x;
  int b = blockIdx.y;
  float s = 0.0f;
  for(int k=0;k<ksplit;k++) s += part[((size_t)k*64 + b)*N + n];
  s += bias[n];
  if(ACT==1) s = sigm(s);
  else if(ACT==2) s = tanhf(s);
  if(mul) s *= mul[(size_t)b*mul_ld + n];
  out[(size_t)b*out_ld + n] = s;
}

// GRU elementwise: r,z,n gates -> h_new; write hidden output + A2 first half
__global__ void k_gru(const float* __restrict__ gi, const float* __restrict__ gh,
                      const float* __restrict__ h0,
                      float* __restrict__ hid_out, float* __restrict__ a2){
  int idx = blockIdx.x*256 + threadIdx.x; // 0..65535
  int b = idx>>10, j = idx&1023;
  const float* gib = gi + (size_t)b*3072;
  const float* ghb = gh + (size_t)b*3072;
  float r = sigm(gib[j] + ghb[j]);
  float z = sigm(gib[1024+j] + ghb[1024+j]);
  float n = tanhf(gib[2048+j] + r*ghb[2048+j]);
  float h = (1.0f-z)*n + z*h0[idx];
  hid_out[idx] = h;
  a2[(size_t)b*2048 + j] = h;
}

// scores[b,s] = dot(h_new[b,:], enc[s,b,:]); one wave per (s,b) pair
__global__ void k_scores(const float* __restrict__ enc, const float* __restrict__ hn,
                         float* __restrict__ sc){
  int p = blockIdx.x*4 + (threadIdx.x>>6);
  int lane = threadIdx.x&63;
  int s = p>>6, b = p&63;
  const float* ep = enc + ((size_t)s*64 + b)*1024;
  const float* hp = hn + (size_t)b*1024;
  float acc = 0.0f;
  #pragma unroll
  for(int it=0; it<4; it++){
    int h = it*256 + lane*4;
    f4 e = *(const f4*)(ep+h); f4 qv = *(const f4*)(hp+h);
    acc += e.x*qv.x + e.y*qv.y + e.z*qv.z + e.w*qv.w;
  }
  acc = wrsum(acc);
  if(lane==0) sc[(size_t)b*SEQ + s] = acc;
}

// softmax over S=256 per row; block b, 256 threads
__global__ void k_softmax(const float* __restrict__ sc, float* __restrict__ aw){
  int b = blockIdx.x; int s = threadIdx.x;
  float v = sc[(size_t)b*SEQ + s];
  __shared__ float r1[4], r2[4];
  int w = s>>6;
  float m = wrmax(v);
  if((s&63)==0) r1[w]=m;
  __syncthreads();
  float mm = fmaxf(fmaxf(r1[0],r1[1]),fmaxf(r1[2],r1[3]));
  float e = expf(v-mm);
  float ss = wrsum(e);
  if((s&63)==0) r2[w]=ss;
  __syncthreads();
  float tot = r2[0]+r2[1]+r2[2]+r2[3];
  aw[(size_t)b*SEQ + s] = e/tot;
}

// context partials: block (b, c): sum over s-chunk c (32 s values)
__global__ void k_ctxp(const float* __restrict__ enc, const float* __restrict__ aw,
                       float* __restrict__ part){
  int b = blockIdx.x, c = blockIdx.y;
  int t = threadIdx.x; int h = t*4;
  __shared__ float wsm[32];
  if(t<32) wsm[t] = aw[(size_t)b*SEQ + c*32 + t];
  __syncthreads();
  f4 acc = {0,0,0,0};
  for(int si=0; si<32; si++){
    float w = wsm[si];
    f4 e = *(const f4*)(enc + ((size_t)(c*32+si)*64 + b)*1024 + h);
    acc.x += w*e.x; acc.y += w*e.y; acc.z += w*e.z; acc.w += w*e.w;
  }
  *(f4*)(part + ((size_t)c*64 + b)*1024 + h) = acc;
}

// reduce 8 context partials -> d_out context + A2 second half
__global__ void k_ctxr(const float* __restrict__ part, float* __restrict__ ctx_out,
                       float* __restrict__ a2){
  int idx = blockIdx.x*256 + threadIdx.x; // f4 units, 16384 total
  int b = idx>>8; int h = (idx&255)*4;
  f4 s = {0,0,0,0};
  #pragma unroll
  for(int c=0;c<8;c++){
    f4 v = *(const f4*)(part + ((size_t)c*64 + b)*1024 + h);
    s.x+=v.x; s.y+=v.y; s.z+=v.z; s.w+=v.w;
  }
  *(f4*)(ctx_out + (size_t)b*1024 + h) = s;
  *(f4*)(a2 + (size_t)b*2048 + 1024 + h) = s;
}

// per-row: alpha dot, masked max, unmasked max
__global__ void k_rowstat(const float* __restrict__ logits, const float* __restrict__ wal,
                          const int* __restrict__ mem, float* __restrict__ stats){
  int b = blockIdx.x; int t = threadIdx.x;
  const float* lp = logits + (size_t)b*V;
  float dot=0.0f, me=-INFINITY, mg=-INFINITY;
  for(int v=t; v<V; v+=256){
    float l = lp[v];
    dot += l*wal[v];
    if(mem[v]==1) me = fmaxf(me,l); else mg = fmaxf(mg,l);
  }
  dot = wrsum(dot); me = wrmax(me); mg = wrmax(mg);
  __shared__ float rd[4], re[4], rg[4];
  int w=t>>6;
  if((t&63)==0){ rd[w]=dot; re[w]=me; rg[w]=mg; }
  __syncthreads();
  if(t==0){
    stats[b*8+0] = rd[0]+rd[1]+rd[2]+rd[3];
    stats[b*8+1] = fmaxf(fmaxf(re[0],re[1]),fmaxf(re[2],re[3]));
    stats[b*8+2] = fmaxf(fmaxf(rg[0],rg[1]),fmaxf(rg[2],rg[3]));
  }
}

// per-row: masked / unmasked exp-sums
__global__ void k_rowsum(const float* __restrict__ logits, const int* __restrict__ mem,
                         float* __restrict__ stats){
  int b = blockIdx.x; int t = threadIdx.x;
  float me = stats[b*8+1], mg = stats[b*8+2];
  const float* lp = logits + (size_t)b*V;
  float se=0.0f, sg=0.0f;
  for(int v=t; v<V; v+=256){
    float l = lp[v];
    if(mem[v]==1) se += expf(l-me); else sg += expf(l-mg);
  }
  se = wrsum(se); sg = wrsum(sg);
  __shared__ float q1[4], q2[4];
  int w=t>>6;
  if((t&63)==0){ q1[w]=se; q2[w]=sg; }
  __syncthreads();
  if(t==0){ stats[b*8+3]=q1[0]+q1[1]+q1[2]+q1[3]; stats[b*8+4]=q2[0]+q2[1]+q2[2]+q2[3]; }
}

// dual gated softmax, in-place over logits region (d_out output)
__global__ void k_final(float* __restrict__ logits, const int* __restrict__ mem,
                        const float* __restrict__ stats, const float* __restrict__ balpha){
  int v = blockIdx.x*256 + threadIdx.x;
  int b = blockIdx.y;
  if(v >= V) return;
  float dot = stats[b*8+0], me = stats[b*8+1], mg = stats[b*8+2];
  float se = stats[b*8+3],  sg = stats[b*8+4];
  float g = sigm(dot + balpha[0]);
  float l = logits[(size_t)b*V + v];
  float o = (mem[v]==1) ? (expf(l-me)/se * g) : (expf(l-mg)/sg * (1.0f-g));
  logits[(size_t)b*V + v] = o;
}

extern "C" void kernel_launch(void* const* d_in, const int* in_sizes, int n_in,
                              void* d_out, int out_size, void* d_ws, size_t ws_size,
                              hipStream_t stream){
  const int*   istep   = (const int*)d_in[0];
  const int*   iemo    = (const int*)d_in[1];
  const float* lasth   = (const float*)d_in[2];
  const float* ictx    = (const float*)d_in[3];
  const float* enc     = (const float*)d_in[4];
  const int*   emem    = (const int*)d_in[5];
  const float* emb     = (const float*)d_in[6];
  const float* eemb    = (const float*)d_in[7];
  const float* W_read  = (const float*)d_in[8];
  const float* b_read  = (const float*)d_in[9];
  const float* W_write = (const float*)d_in[10];
  const float* b_write = (const float*)d_in[11];
  const float* W_ih    = (const float*)d_in[12];
  const float* W_hh    = (const float*)d_in[13];
  const float* b_ih    = (const float*)d_in[14];
  const float* b_hh    = (const float*)d_in[15];
  const float* W_concat= (const float*)d_in[16];
  const float* b_concat= (const float*)d_in[17];
  const float* W_out   = (const float*)d_in[18];
  const float* b_out   = (const float*)d_in[19];
  const float* W_alpha = (const float*)d_in[20];
  const float* b_alpha = (const float*)d_in[21];

  float* ws    = (float*)d_ws;
  float* X     = ws;                 // 64*4096
  float* emo   = X + 262144;         // 64*1024
  float* gi    = emo + 65536;        // 64*3072
  float* gh    = gi + 196608;        // 64*3072
  float* sc    = gh + 196608;        // 64*256
  float* aw    = sc + 16384;         // 64*256
  float* cpart = aw + 16384;         // 8*64*1024
  float* a2    = cpart + 524288;     // 64*2048
  float* cc    = a2 + 131072;        // 64*1024
  float* gpart = cc + 65536;         // up to 8*64*3072 = 1572864
  float* stats = gpart + 1572864;    // 512

  float* out0 = (float*)d_out;            // [64][V] (used as logits scratch, then final output)
  float* hid  = out0 + (size_t)B*V;       // [64][1024]
  float* memo = hid + 65536;              // [64][1024]
  float* ctxo = memo + 65536;             // [64][1024]

  // 1. gather/build
  k_build<<<64,256,0,stream>>>(istep, iemo, lasth, ictx, emb, eemb, X, emo);
  // 2. M_read = sigmoid(A1 @ W_read.T + b_read); emo_g = emo*M_read -> X[:,3072:]
  k_gemm<false><<<dim3(16,16),256,0,stream>>>(X, 4096, W_read, 3072, 1024, 192, nullptr, gpart, 0);
  k_reduce<1><<<dim3(4,64),256,0,stream>>>(gpart, 16, 1024, b_read, emo, 1024, X+3072, 4096);
  // 3. gi = X @ W_ih.T + b_ih
  k_gemm<false><<<dim3(48,8),256,0,stream>>>(X, 4096, W_ih, 4096, 3072, 512, nullptr, gpart, 0);
  k_reduce<0><<<dim3(12,64),256,0,stream>>>(gpart, 8, 3072, b_ih, nullptr, 0, gi, 3072);
  // 4. gh = h0 @ W_hh.T + b_hh
  k_gemm<false><<<dim3(48,8),256,0,stream>>>(lasth, 1024, W_hh, 1024, 3072, 128, nullptr, gpart, 0);
  k_reduce<0><<<dim3(12,64),256,0,stream>>>(gpart, 8, 3072, b_hh, nullptr, 0, gh, 3072);
  // 5. GRU elementwise -> hidden output + A2[:, :1024]
  k_gru<<<256,256,0,stream>>>(gi, gh, lasth, hid, a2);
  // 6. new_M_emo = sigmoid(h_new @ W_write.T + b_write) * emo_g
  k_gemm<false><<<dim3(16,16),256,0,stream>>>(hid, 1024, W_write, 1024, 1024, 64, nullptr, gpart, 0);
  k_reduce<1><<<dim3(4,64),256,0,stream>>>(gpart, 16, 1024, b_write, X+3072, 4096, memo, 1024);
  // 7. attention
  k_scores<<<4096,256,0,stream>>>(enc, hid, sc);
  k_softmax<<<64,256,0,stream>>>(sc, aw);
  k_ctxp<<<dim3(64,8),256,0,stream>>>(enc, aw, cpart);
  k_ctxr<<<64,256,0,stream>>>(cpart, ctxo, a2);
  // 8. concat_out = tanh(A2 @ W_concat.T + b_concat)
  k_gemm<false><<<dim3(16,16),256,0,stream>>>(a2, 2048, W_concat, 2048, 1024, 128, nullptr, gpart, 0);
  k_reduce<2><<<dim3(4,64),256,0,stream>>>(gpart, 16, 1024, b_concat, nullptr, 0, cc, 1024);
  // 9. logits = concat_out @ W_out.T + b_out  (direct, into d_out output region)
  k_gemm<true><<<dim3(786,1),256,0,stream>>>(cc, 1024, W_out, 1024, V, 1024, b_out, out0, V);
  // 10. gated dual softmax
  k_rowstat<<<64,256,0,stream>>>(out0, W_alpha, emem, stats);
  k_rowsum<<<64,256,0,stream>>>(out0, emem, stats);
  k_final<<<dim3((V+255)/256,64),256,0,stream>>>(out0, emem, stats, b_alpha);
}

// Round 2
// 314.064 us; speedup vs baseline: 1.3208x; 1.3208x over previous
//
#include <hip/hip_runtime.h>
#include <hip/hip_bf16.h>
#include <math.h>

#define B 64
#define H 1024
#define SEQ 256
#define V 50257

typedef float4 f4;
typedef __attribute__((ext_vector_type(4))) float f32x4;
typedef __attribute__((ext_vector_type(8))) short bf16x8;   // 8 bf16 in 4 VGPRs

__device__ inline float sigm(float x){ return 1.0f/(1.0f+expf(-x)); }

__device__ inline short f2bf(float x){
  __hip_bfloat16 h = __float2bfloat16(x);
  union { __hip_bfloat16 h; short s; } u; u.h = h; return u.s;
}
__device__ inline short2 cvt2(float x, float y){
  __hip_bfloat162 h = __float22bfloat162_rn(float2{x, y});
  union { __hip_bfloat162 h; short2 s; } u; u.h = h; return u.s;
}
__device__ inline bf16x8 pack8(f4 lo, f4 hi){
  union { bf16x8 v; short2 s[4]; } u;
  u.s[0]=cvt2(lo.x,lo.y); u.s[1]=cvt2(lo.z,lo.w);
  u.s[2]=cvt2(hi.x,hi.y); u.s[3]=cvt2(hi.z,hi.w);
  return u.v;
}
__device__ inline float wrsum(float v){
  #pragma unroll
  for(int o=32;o;o>>=1) v += __shfl_xor(v,o);
  return v;
}

// ---------- build: X_b[:, :3H] = bf16[lw | lasth | ctx]; emo f32 ----------
__global__ void k_build(const int* __restrict__ istep, const int* __restrict__ iemo,
                        const float* __restrict__ lasth, const float* __restrict__ ictx,
                        const float* __restrict__ emb, const float* __restrict__ eemb,
                        short* __restrict__ X_b, float* __restrict__ emo){
  int b = blockIdx.x; int h = threadIdx.x*4;
  int iw = istep[b], ie = iemo[b];
  f4 lw = *(const f4*)(emb  + (size_t)iw*H + h);
  f4 hs = *(const f4*)(lasth + (size_t)b*H + h);
  f4 cv = *(const f4*)(ictx + (size_t)b*H + h);
  f4 ev = *(const f4*)(eemb + (size_t)ie*H + h);
  *(f4*)(emo + (size_t)b*H + h) = ev;
  short* xb = X_b + (size_t)b*4096;
  *(short4*)(xb +        h) = make_short4(f2bf(lw.x),f2bf(lw.y),f2bf(lw.z),f2bf(lw.w));
  *(short4*)(xb + 1024 + h) = make_short4(f2bf(hs.x),f2bf(hs.y),f2bf(hs.z),f2bf(hs.w));
  *(short4*)(xb + 2048 + h) = make_short4(f2bf(cv.x),f2bf(cv.y),f2bf(cv.z),f2bf(cv.w));
}

// ---------- MFMA GEMM, direct mode (W_out): out[64,N] = A_b @ W^T + bias ----------
// block: 4 waves, each wave 16 n-cols x 64 m rows, full K. No LDS, no barriers.
__launch_bounds__(256)
__global__ void k_mgemm_out(const short* __restrict__ A, int lda,
                            const float* __restrict__ Wm, int K, int N,
                            const float* __restrict__ bias,
                            float* __restrict__ outf, int ldf){
  int tid = threadIdx.x;
  int w = tid>>6, l = tid&63;
  int lm = l&15, lq = l>>4;
  int n_base = blockIdx.x*64 + w*16;
  int ncol = n_base + lm;
  int nrow = ncol < N ? ncol : N-1;
  const float* wp = Wm + (size_t)nrow*K + lq*8;
  const short* ap = A + lm*lda + lq*8;

  f32x4 acc0={0,0,0,0}, acc1={0,0,0,0}, acc2={0,0,0,0}, acc3={0,0,0,0};
  for(int k0=0; k0<K; k0+=64){
    f4 w0 = *(const f4*)(wp + k0);
    f4 w1 = *(const f4*)(wp + k0 + 4);
    f4 w2 = *(const f4*)(wp + k0 + 32);
    f4 w3 = *(const f4*)(wp + k0 + 36);
    bf16x8 a00 = *(const bf16x8*)(ap + k0);
    bf16x8 a01 = *(const bf16x8*)(ap + k0 + 32);
    bf16x8 a10 = *(const bf16x8*)(ap + 16*lda + k0);
    bf16x8 a11 = *(const bf16x8*)(ap + 16*lda + k0 + 32);
    bf16x8 a20 = *(const bf16x8*)(ap + 32*lda + k0);
    bf16x8 a21 = *(const bf16x8*)(ap + 32*lda + k0 + 32);
    bf16x8 a30 = *(const bf16x8*)(ap + 48*lda + k0);
    bf16x8 a31 = *(const bf16x8*)(ap + 48*lda + k0 + 32);
    bf16x8 b0 = pack8(w0,w1), b1 = pack8(w2,w3);
    acc0 = __builtin_amdgcn_mfma_f32_16x16x32_bf16(a00,b0,acc0,0,0,0);
    acc1 = __builtin_amdgcn_mfma_f32_16x16x32_bf16(a10,b0,acc1,0,0,0);
    acc2 = __builtin_amdgcn_mfma_f32_16x16x32_bf16(a20,b0,acc2,0,0,0);
    acc3 = __builtin_amdgcn_mfma_f32_16x16x32_bf16(a30,b0,acc3,0,0,0);
    acc0 = __builtin_amdgcn_mfma_f32_16x16x32_bf16(a01,b1,acc0,0,0,0);
    acc1 = __builtin_amdgcn_mfma_f32_16x16x32_bf16(a11,b1,acc1,0,0,0);
    acc2 = __builtin_amdgcn_mfma_f32_16x16x32_bf16(a21,b1,acc2,0,0,0);
    acc3 = __builtin_amdgcn_mfma_f32_16x16x32_bf16(a31,b1,acc3,0,0,0);
  }
  if(ncol < N){
    float bv = bias[ncol];
    #pragma unroll
    for(int r=0;r<4;r++){
      int m0 = lq*4 + r;
      outf[(size_t)(m0     )*ldf + ncol] = acc0[r] + bv;
      outf[(size_t)(m0 + 16)*ldf + ncol] = acc1[r] + bv;
      outf[(size_t)(m0 + 32)*ldf + ncol] = acc2[r] + bv;
      outf[(size_t)(m0 + 48)*ldf + ncol] = acc3[r] + bv;
    }
  }
}

// ---------- MFMA GEMM, partial mode: block = 16 n-cols, 4 waves = 4 K-slices ----------
// grid = (N/16, nysplit); wave k-range = (by*4+w)*kslice .. +kslice. Raw partial out.
__launch_bounds__(256)
__global__ void k_mgemm_part(const short* __restrict__ A, int lda,
                             const float* __restrict__ Wm, int K, int N, int kslice,
                             float* __restrict__ outp){
  int tid = threadIdx.x;
  int w = tid>>6, l = tid&63;
  int lm = l&15, lq = l>>4;
  int n_base = blockIdx.x*16;
  int ncol = n_base + lm;
  int kbeg = (blockIdx.y*4 + w)*kslice, kend = kbeg + kslice;
  const float* wp = Wm + (size_t)ncol*K + lq*8;
  const short* ap = A + lm*lda + lq*8;

  f32x4 acc0={0,0,0,0}, acc1={0,0,0,0}, acc2={0,0,0,0}, acc3={0,0,0,0};
  for(int k0=kbeg; k0<kend; k0+=64){
    f4 w0 = *(const f4*)(wp + k0);
    f4 w1 = *(const f4*)(wp + k0 + 4);
    f4 w2 = *(const f4*)(wp + k0 + 32);
    f4 w3 = *(const f4*)(wp + k0 + 36);
    bf16x8 a00 = *(const bf16x8*)(ap + k0);
    bf16x8 a01 = *(const bf16x8*)(ap + k0 + 32);
    bf16x8 a10 = *(const bf16x8*)(ap + 16*lda + k0);
    bf16x8 a11 = *(const bf16x8*)(ap + 16*lda + k0 + 32);
    bf16x8 a20 = *(const bf16x8*)(ap + 32*lda + k0);
    bf16x8 a21 = *(const bf16x8*)(ap + 32*lda + k0 + 32);
    bf16x8 a30 = *(const bf16x8*)(ap + 48*lda + k0);
    bf16x8 a31 = *(const bf16x8*)(ap + 48*lda + k0 + 32);
    bf16x8 b0 = pack8(w0,w1), b1 = pack8(w2,w3);
    acc0 = __builtin_amdgcn_mfma_f32_16x16x32_bf16(a00,b0,acc0,0,0,0);
    acc1 = __builtin_amdgcn_mfma_f32_16x16x32_bf16(a10,b0,acc1,0,0,0);
    acc2 = __builtin_amdgcn_mfma_f32_16x16x32_bf16(a20,b0,acc2,0,0,0);
    acc3 = __builtin_amdgcn_mfma_f32_16x16x32_bf16(a30,b0,acc3,0,0,0);
    acc0 = __builtin_amdgcn_mfma_f32_16x16x32_bf16(a01,b1,acc0,0,0,0);
    acc1 = __builtin_amdgcn_mfma_f32_16x16x32_bf16(a11,b1,acc1,0,0,0);
    acc2 = __builtin_amdgcn_mfma_f32_16x16x32_bf16(a21,b1,acc2,0,0,0);
    acc3 = __builtin_amdgcn_mfma_f32_16x16x32_bf16(a31,b1,acc3,0,0,0);
  }
  __shared__ float red[4][64][20];
  #pragma unroll
  for(int r=0;r<4;r++){
    red[w][     lq*4+r][lm] = acc0[r];
    red[w][16 + lq*4+r][lm] = acc1[r];
    red[w][32 + lq*4+r][lm] = acc2[r];
    red[w][48 + lq*4+r][lm] = acc3[r];
  }
  __syncthreads();
  int m = tid>>2;
  float* op = outp + ((size_t)blockIdx.y*64 + m)*N + n_base;
  #pragma unroll
  for(int j=0;j<4;j++){
    int c = (tid&3)*4 + j;
    op[c] = red[0][m][c]+red[1][m][c]+red[2][m][c]+red[3][m][c];
  }
}

// ---------- combine partials + bias + act (+mul), write f32 and/or bf16 ----------
template<int ACT, bool MUL, bool OUTF32, bool OUTBF>
__global__ void k_comb(const float* __restrict__ part, int np, int N,
                       const float* __restrict__ bias,
                       const float* __restrict__ mul, int mul_ld,
                       float* __restrict__ outf, int ldf,
                       short* __restrict__ outb, int ldb2){
  int n = blockIdx.x*256 + threadIdx.x;
  int b = blockIdx.y;
  float s = 0.0f;
  for(int p=0;p<np;p++) s += part[((size_t)p*64 + b)*N + n];
  s += bias[n];
  if(ACT==1) s = sigm(s); else if(ACT==2) s = tanhf(s);
  if(MUL) s *= mul[(size_t)b*mul_ld + n];
  if(OUTF32) outf[(size_t)b*ldf + n] = s;
  if(OUTBF)  outb[(size_t)b*ldb2 + n] = f2bf(s);
}

// ---------- GRU elementwise; folds gi/gh partial combine + biases ----------
__global__ void k_gru(const float* __restrict__ pgi, const float* __restrict__ pgh,
                      const float* __restrict__ bih, const float* __restrict__ bhh,
                      const float* __restrict__ h0,
                      float* __restrict__ hid, short* __restrict__ hid_b,
                      short* __restrict__ a2_b){
  int t = blockIdx.x*256 + threadIdx.x;   // 16384 threads, 4 elems each
  int b = t>>8, j = (t&255)*4;
  const float* gi0 = pgi + (size_t)b*3072 + j;
  const float* gi1 = pgi + (size_t)(64+b)*3072 + j;
  const float* gh0 = pgh + (size_t)b*3072 + j;
  const float* gh1 = pgh + (size_t)(64+b)*3072 + j;
  f4 hres; short4 hb;
  f4 h0v = *(const f4*)(h0 + (size_t)b*1024 + j);
  #pragma unroll
  for(int c=0;c<4;c++){
    float ir = gi0[c]      + gi1[c]      + bih[j+c];
    float iz = gi0[1024+c] + gi1[1024+c] + bih[1024+j+c];
    float in = gi0[2048+c] + gi1[2048+c] + bih[2048+j+c];
    float hr = gh0[c]      + gh1[c]      + bhh[j+c];
    float hz = gh0[1024+c] + gh1[1024+c] + bhh[1024+j+c];
    float hn = gh0[2048+c] + gh1[2048+c] + bhh[2048+j+c];
    float r = sigm(ir + hr);
    float z = sigm(iz + hz);
    float n = tanhf(in + r*hn);
    float hv = ((const float*)&h0v)[c];
    float h = (1.0f - z)*n + z*hv;
    ((float*)&hres)[c] = h;
    ((short*)&hb)[c] = f2bf(h);
  }
  *(f4*)(hid + (size_t)b*1024 + j) = hres;
  *(short4*)(hid_b + (size_t)b*1024 + j) = hb;
  *(short4*)(a2_b + (size_t)b*2048 + j) = hb;
}

// ---------- attention ----------
__global__ void k_scores(const float* __restrict__ enc, const float* __restrict__ hn,
                         float* __restrict__ sc){
  int p = blockIdx.x*4 + (threadIdx.x>>6);
  int lane = threadIdx.x&63;
  int s = p>>6, b = p&63;
  const float* ep = enc + ((size_t)s*64 + b)*1024;
  const float* hp = hn + (size_t)b*1024;
  float acc = 0.0f;
  #pragma unroll
  for(int it=0; it<4; it++){
    int h = it*256 + lane*4;
    f4 e = *(const f4*)(ep+h); f4 qv = *(const f4*)(hp+h);
    acc += e.x*qv.x + e.y*qv.y + e.z*qv.z + e.w*qv.w;
  }
  acc = wrsum(acc);
  if(lane==0) sc[(size_t)b*SEQ + s] = acc;
}

__global__ void k_softmax(const float* __restrict__ sc, float* __restrict__ aw){
  int b = blockIdx.x; int s = threadIdx.x;
  float v = sc[(size_t)b*SEQ + s];
  __shared__ float r1[4], r2[4];
  int w = s>>6;
  float m = v;
  #pragma unroll
  for(int o=32;o;o>>=1) m = fmaxf(m,__shfl_xor(m,o));
  if((s&63)==0) r1[w]=m;
  __syncthreads();
  float mm = fmaxf(fmaxf(r1[0],r1[1]),fmaxf(r1[2],r1[3]));
  float e = expf(v-mm);
  float ss = wrsum(e);
  if((s&63)==0) r2[w]=ss;
  __syncthreads();
  float tot = r2[0]+r2[1]+r2[2]+r2[3];
  aw[(size_t)b*SEQ + s] = e/tot;
}

__global__ void k_ctxp(const float* __restrict__ enc, const float* __restrict__ aw,
                       float* __restrict__ part){
  int b = blockIdx.x, c = blockIdx.y;
  int t = threadIdx.x; int h = t*4;
  __shared__ float wsm[32];
  if(t<32) wsm[t] = aw[(size_t)b*SEQ + c*32 + t];
  __syncthreads();
  f4 acc = {0,0,0,0};
  for(int si=0; si<32; si++){
    float w = wsm[si];
    f4 e = *(const f4*)(enc + ((size_t)(c*32+si)*64 + b)*1024 + h);
    acc.x += w*e.x; acc.y += w*e.y; acc.z += w*e.z; acc.w += w*e.w;
  }
  *(f4*)(part + ((size_t)c*64 + b)*1024 + h) = acc;
}

__global__ void k_ctxr(const float* __restrict__ part, float* __restrict__ ctx_out,
                       short* __restrict__ a2_b){
  int idx = blockIdx.x*256 + threadIdx.x;
  int b = idx>>8; int h = (idx&255)*4;
  f4 s = {0,0,0,0};
  #pragma unroll
  for(int c=0;c<8;c++){
    f4 v = *(const f4*)(part + ((size_t)c*64 + b)*1024 + h);
    s.x+=v.x; s.y+=v.y; s.z+=v.z; s.w+=v.w;
  }
  *(f4*)(ctx_out + (size_t)b*1024 + h) = s;
  *(short4*)(a2_b + (size_t)b*2048 + 1024 + h) = make_short4(f2bf(s.x),f2bf(s.y),f2bf(s.z),f2bf(s.w));
}

// ---------- single-pass row stats: alpha-dot + online (max,sum) per group ----------
__global__ void k_rowpass(const float* __restrict__ logits, const float* __restrict__ wal,
                          const int* __restrict__ mem, float* __restrict__ stats){
  int b = blockIdx.x, t = threadIdx.x;
  const float* lp = logits + (size_t)b*V;
  float dot=0.0f, me=-1e30f, se=0.0f, mg=-1e30f, sg=0.0f;
  for(int v=t; v<V; v+=256){
    float l = lp[v];
    dot += l*wal[v];
    if(mem[v]==1){
      if(l<=me) se += expf(l-me); else { se = se*expf(me-l) + 1.0f; me = l; }
    } else {
      if(l<=mg) sg += expf(l-mg); else { sg = sg*expf(mg-l) + 1.0f; mg = l; }
    }
  }
  #pragma unroll
  for(int o=32;o;o>>=1){
    float me2=__shfl_xor(me,o), se2=__shfl_xor(se,o);
    float m = fmaxf(me,me2); se = se*expf(me-m) + se2*expf(me2-m); me = m;
    float mg2=__shfl_xor(mg,o), sg2=__shfl_xor(sg,o);
    float m2 = fmaxf(mg,mg2); sg = sg*expf(mg-m2) + sg2*expf(mg2-m2); mg = m2;
    dot += __shfl_xor(dot,o);
  }
  __shared__ float sm[4][5];
  int wv = t>>6;
  if((t&63)==0){ sm[wv][0]=dot; sm[wv][1]=me; sm[wv][2]=se; sm[wv][3]=mg; sm[wv][4]=sg; }
  __syncthreads();
  if(t==0){
    float D=0, M=-1e30f, S=0, M2=-1e30f, S2=0;
    for(int i=0;i<4;i++){
      D += sm[i][0];
      float m = fmaxf(M, sm[i][1]); S  = S*expf(M-m)  + sm[i][2]*expf(sm[i][1]-m);  M = m;
      float n = fmaxf(M2,sm[i][3]); S2 = S2*expf(M2-n)+ sm[i][4]*expf(sm[i][3]-n); M2 = n;
    }
    stats[b*8+0]=D; stats[b*8+1]=M; stats[b*8+2]=M2; stats[b*8+3]=S; stats[b*8+4]=S2;
  }
}

__global__ void k_final(float* __restrict__ logits, const int* __restrict__ mem,
                        const float* __restrict__ stats, const float* __restrict__ balpha){
  int v = blockIdx.x*256 + threadIdx.x;
  int b = blockIdx.y;
  if(v >= V) return;
  float dot = stats[b*8+0], me = stats[b*8+1], mg = stats[b*8+2];
  float se = stats[b*8+3],  sg = stats[b*8+4];
  float g = sigm(dot + balpha[0]);
  float l = logits[(size_t)b*V + v];
  float o = (mem[v]==1) ? (expf(l-me)/se * g) : (expf(l-mg)/sg * (1.0f-g));
  logits[(size_t)b*V + v] = o;
}

extern "C" void kernel_launch(void* const* d_in, const int* in_sizes, int n_in,
                              void* d_out, int out_size, void* d_ws, size_t ws_size,
                              hipStream_t stream){
  const int*   istep   = (const int*)d_in[0];
  const int*   iemo    = (const int*)d_in[1];
  const float* lasth   = (const float*)d_in[2];
  const float* ictx    = (const float*)d_in[3];
  const float* enc     = (const float*)d_in[4];
  const int*   emem    = (const int*)d_in[5];
  const float* emb     = (const float*)d_in[6];
  const float* eemb    = (const float*)d_in[7];
  const float* W_read  = (const float*)d_in[8];
  const float* b_read  = (const float*)d_in[9];
  const float* W_write = (const float*)d_in[10];
  const float* b_write = (const float*)d_in[11];
  const float* W_ih    = (const float*)d_in[12];
  const float* W_hh    = (const float*)d_in[13];
  const float* b_ih    = (const float*)d_in[14];
  const float* b_hh    = (const float*)d_in[15];
  const float* W_concat= (const float*)d_in[16];
  const float* b_concat= (const float*)d_in[17];
  const float* W_out   = (const float*)d_in[18];
  const float* b_out   = (const float*)d_in[19];
  const float* W_alpha = (const float*)d_in[20];
  const float* b_alpha = (const float*)d_in[21];

  // workspace layout
  short* X_b  = (short*)d_ws;                           // 64x4096 bf16 (512 KB)
  float* emo  = (float*)((char*)d_ws + 524288);         // 64x1024
  float* emog = emo + 65536;                            // 64x1024
  float* sc   = emog + 65536;                           // 64x256
  float* aw   = sc + 16384;                             // 64x256
  float* stats= aw + 16384;                             // 512
  float* ppA  = stats + 512;                            // 4x64x1024
  float* ppB  = ppA + 262144;                           // 2x64x3072 (gi)
  float* ppC  = ppB + 393216;                           // 2x64x3072 (gh)
  float* cpart= ppC + 393216;                           // 8x64x1024
  short* hid_b= (short*)(cpart + 524288);               // 64x1024 bf16
  short* a2_b = hid_b + 65536;                          // 64x2048 bf16
  short* cc_b = a2_b + 131072;                          // 64x1024 bf16

  float* out0 = (float*)d_out;                          // [64][V] logits -> final output
  float* hid  = out0 + (size_t)B*V;                     // [64][1024]
  float* memo = hid + 65536;                            // [64][1024]
  float* ctxo = memo + 65536;                           // [64][1024]

  // 1. gather + bf16 X build
  k_build<<<64,256,0,stream>>>(istep, iemo, lasth, ictx, emb, eemb, X_b, emo);
  // 2. M_read: sigmoid(.)*emo -> emog f32, X_b[:,3072:] bf16
  k_mgemm_part<<<dim3(64,4),256,0,stream>>>(X_b, 4096, W_read, 3072, 1024, 192, ppA);
  k_comb<1,true,true,true><<<dim3(4,64),256,0,stream>>>(ppA, 4, 1024, b_read, emo, 1024, emog, 1024, X_b+3072, 4096);
  // 3. gi partials
  k_mgemm_part<<<dim3(192,2),256,0,stream>>>(X_b, 4096, W_ih, 4096, 3072, 512, ppB);
  // 4. gh partials
  k_mgemm_part<<<dim3(192,2),256,0,stream>>>(X_b+1024, 4096, W_hh, 1024, 3072, 128, ppC);
  // 5. GRU (folds partial combine + biases)
  k_gru<<<64,256,0,stream>>>(ppB, ppC, b_ih, b_hh, lasth, hid, hid_b, a2_b);
  // 6. new_M_emo = sigmoid(hid@W_write^T+b)*emog
  k_mgemm_part<<<dim3(64,4),256,0,stream>>>(hid_b, 1024, W_write, 1024, 1024, 64, ppA);
  k_comb<1,true,true,false><<<dim3(4,64),256,0,stream>>>(ppA, 4, 1024, b_write, emog, 1024, memo, 1024, nullptr, 0);
  // 7. attention
  k_scores<<<4096,256,0,stream>>>(enc, hid, sc);
  k_softmax<<<64,256,0,stream>>>(sc, aw);
  k_ctxp<<<dim3(64,8),256,0,stream>>>(enc, aw, cpart);
  k_ctxr<<<64,256,0,stream>>>(cpart, ctxo, a2_b);
  // 8. concat_out = tanh(a2@W_concat^T+b) -> cc_b bf16
  k_mgemm_part<<<dim3(64,4),256,0,stream>>>(a2_b, 2048, W_concat, 2048, 1024, 128, ppA);
  k_comb<2,false,false,true><<<dim3(4,64),256,0,stream>>>(ppA, 4, 1024, b_concat, nullptr, 0, nullptr, 0, cc_b, 1024);
  // 9. logits = cc@W_out^T + b_out (direct MFMA, streams 206 MB)
  k_mgemm_out<<<786,256,0,stream>>>(cc_b, 1024, W_out, 1024, V, b_out, out0, V);
  // 10. gated dual softmax (single stats pass + finalize)
  k_rowpass<<<64,256,0,stream>>>(out0, W_alpha, emem, stats);
  k_final<<<dim3(197,64),256,0,stream>>>(out0, emem, stats, b_alpha);
}

// Round 6
// 301.130 us; speedup vs baseline: 1.3776x; 1.0430x over previous
//
#include <hip/hip_runtime.h>
#include <hip/hip_bf16.h>
#include <math.h>

#define B 64
#define H 1024
#define SEQ 256
#define V 50257

typedef float4 f4;
typedef __attribute__((ext_vector_type(4))) float f32x4;
typedef __attribute__((ext_vector_type(8))) short bf16x8;

__device__ inline float sigm(float x){ return 1.0f/(1.0f+expf(-x)); }
__device__ inline short f2bf(float x){
  __hip_bfloat16 h = __float2bfloat16(x);
  union { __hip_bfloat16 h; short s; } u; u.h = h; return u.s;
}
__device__ inline short2 cvt2(float x, float y){
  __hip_bfloat162 h = __float22bfloat162_rn(float2{x, y});
  union { __hip_bfloat162 h; short2 s; } u; u.h = h; return u.s;
}
__device__ inline bf16x8 pack8(f4 lo, f4 hi){
  union { bf16x8 v; short2 s[4]; } u;
  u.s[0]=cvt2(lo.x,lo.y); u.s[1]=cvt2(lo.z,lo.w);
  u.s[2]=cvt2(hi.x,hi.y); u.s[3]=cvt2(hi.z,hi.w);
  return u.v;
}
__device__ inline float wrsum(float v){
  #pragma unroll
  for(int o=32;o;o>>=1) v += __shfl_xor(v,o);
  return v;
}
__device__ inline float wrmax(float v){
  #pragma unroll
  for(int o=32;o;o>>=1) v = fmaxf(v,__shfl_xor(v,o));
  return v;
}
__device__ inline f32x4 mfma16(bf16x8 a, bf16x8 b, f32x4 c){
  return __builtin_amdgcn_mfma_f32_16x16x32_bf16(a,b,c,0,0,0);
}

// ---- 1: build X_b[:, :3072] = bf16[emb(iw) | lasth | ictx] ----
__global__ void k_build(const int* __restrict__ istep,
                        const float* __restrict__ lasth, const float* __restrict__ ictx,
                        const float* __restrict__ emb, short* __restrict__ X_b){
  int b = blockIdx.x; int h = threadIdx.x*4;
  int iw = istep[b];
  f4 lw = *(const f4*)(emb  + (size_t)iw*H + h);
  f4 hs = *(const f4*)(lasth + (size_t)b*H + h);
  f4 cv = *(const f4*)(ictx + (size_t)b*H + h);
  short* xb = X_b + (size_t)b*4096;
  *(short4*)(xb +        h) = make_short4(f2bf(lw.x),f2bf(lw.y),f2bf(lw.z),f2bf(lw.w));
  *(short4*)(xb + 1024 + h) = make_short4(f2bf(hs.x),f2bf(hs.y),f2bf(hs.z),f2bf(hs.w));
  *(short4*)(xb + 2048 + h) = make_short4(f2bf(cv.x),f2bf(cv.y),f2bf(cv.z),f2bf(cv.w));
}

// ---- 2: blocks 0..63: W_read gemm + sigmoid*eemb epilogue -> emog f32 + X_b[:,3072:] bf16
//         blocks 64..255: W_hh gemm (192 tiles) -> gh raw f32 ----
__launch_bounds__(256)
__global__ void k_pre(const int* __restrict__ iemo, const short* __restrict__ X_b,
                      const float* __restrict__ eemb,
                      const float* __restrict__ Wread, const float* __restrict__ bread,
                      const float* __restrict__ Whh,
                      float* __restrict__ emog, short* __restrict__ X_b_w,
                      float* __restrict__ gh){
  __shared__ float red[4][64][20];
  int tid = threadIdx.x;
  int w = tid>>6, l = tid&63, lm = l&15, lq = l>>4;
  f32x4 acc0={0,0,0,0}, acc1={0,0,0,0}, acc2={0,0,0,0}, acc3={0,0,0,0};
  int readmode = (blockIdx.x < 64);
  int tile = readmode ? blockIdx.x : (blockIdx.x - 64);
  int ncol = tile*16 + lm;
  const float* wp = readmode ? (Wread + (size_t)ncol*3072 + lq*8)
                             : (Whh   + (size_t)ncol*1024 + lq*8);
  const short* ap = readmode ? (X_b + lm*4096 + lq*8)
                             : (X_b + 1024 + lm*4096 + lq*8);
  int kbeg = readmode ? w*768 : w*256;
  int kend = readmode ? (kbeg + 768) : (kbeg + 256);
  for(int k0=kbeg; k0<kend; k0+=64){
    f4 w0 = *(const f4*)(wp + k0);
    f4 w1 = *(const f4*)(wp + k0 + 4);
    f4 w2 = *(const f4*)(wp + k0 + 32);
    f4 w3 = *(const f4*)(wp + k0 + 36);
    bf16x8 a00 = *(const bf16x8*)(ap + k0);
    bf16x8 a01 = *(const bf16x8*)(ap + k0 + 32);
    bf16x8 a10 = *(const bf16x8*)(ap + 16*4096 + k0);
    bf16x8 a11 = *(const bf16x8*)(ap + 16*4096 + k0 + 32);
    bf16x8 a20 = *(const bf16x8*)(ap + 32*4096 + k0);
    bf16x8 a21 = *(const bf16x8*)(ap + 32*4096 + k0 + 32);
    bf16x8 a30 = *(const bf16x8*)(ap + 48*4096 + k0);
    bf16x8 a31 = *(const bf16x8*)(ap + 48*4096 + k0 + 32);
    bf16x8 b0 = pack8(w0,w1), b1 = pack8(w2,w3);
    acc0 = mfma16(a00,b0,acc0); acc1 = mfma16(a10,b0,acc1);
    acc2 = mfma16(a20,b0,acc2); acc3 = mfma16(a30,b0,acc3);
    acc0 = mfma16(a01,b1,acc0); acc1 = mfma16(a11,b1,acc1);
    acc2 = mfma16(a21,b1,acc2); acc3 = mfma16(a31,b1,acc3);
  }
  #pragma unroll
  for(int r=0;r<4;r++){
    red[w][     lq*4+r][lm] = acc0[r];
    red[w][16 + lq*4+r][lm] = acc1[r];
    red[w][32 + lq*4+r][lm] = acc2[r];
    red[w][48 + lq*4+r][lm] = acc3[r];
  }
  __syncthreads();
  int m = tid>>2;
  if(readmode){
    int ie = iemo[m];
    #pragma unroll
    for(int j=0;j<4;j++){
      int c = (tid&3)*4 + j;
      float v = red[0][m][c]+red[1][m][c]+red[2][m][c]+red[3][m][c];
      int n = tile*16 + c;
      float s = sigm(v + bread[n]);
      float eg = s * eemb[(size_t)ie*1024 + n];
      emog[(size_t)m*1024 + n] = eg;
      X_b_w[(size_t)m*4096 + 3072 + n] = f2bf(eg);
    }
  } else {
    #pragma unroll
    for(int j=0;j<4;j++){
      int c = (tid&3)*4 + j;
      float v = red[0][m][c]+red[1][m][c]+red[2][m][c]+red[3][m][c];
      gh[(size_t)m*3072 + tile*16 + c] = v;
    }
  }
}

// ---- 3: gi = X @ W_ih^T (raw, K=4096) ----
__launch_bounds__(256)
__global__ void k_gi(const short* __restrict__ X_b, const float* __restrict__ Wih,
                     float* __restrict__ gi){
  __shared__ float red[4][64][20];
  int tid = threadIdx.x;
  int w = tid>>6, l = tid&63, lm = l&15, lq = l>>4;
  int ncol = blockIdx.x*16 + lm;
  const float* wp = Wih + (size_t)ncol*4096 + lq*8;
  const short* ap = X_b + lm*4096 + lq*8;
  int kbeg = w*1024, kend = kbeg + 1024;
  f32x4 acc0={0,0,0,0}, acc1={0,0,0,0}, acc2={0,0,0,0}, acc3={0,0,0,0};
  for(int k0=kbeg; k0<kend; k0+=64){
    f4 w0 = *(const f4*)(wp + k0);
    f4 w1 = *(const f4*)(wp + k0 + 4);
    f4 w2 = *(const f4*)(wp + k0 + 32);
    f4 w3 = *(const f4*)(wp + k0 + 36);
    bf16x8 a00 = *(const bf16x8*)(ap + k0);
    bf16x8 a01 = *(const bf16x8*)(ap + k0 + 32);
    bf16x8 a10 = *(const bf16x8*)(ap + 16*4096 + k0);
    bf16x8 a11 = *(const bf16x8*)(ap + 16*4096 + k0 + 32);
    bf16x8 a20 = *(const bf16x8*)(ap + 32*4096 + k0);
    bf16x8 a21 = *(const bf16x8*)(ap + 32*4096 + k0 + 32);
    bf16x8 a30 = *(const bf16x8*)(ap + 48*4096 + k0);
    bf16x8 a31 = *(const bf16x8*)(ap + 48*4096 + k0 + 32);
    bf16x8 b0 = pack8(w0,w1), b1 = pack8(w2,w3);
    acc0 = mfma16(a00,b0,acc0); acc1 = mfma16(a10,b0,acc1);
    acc2 = mfma16(a20,b0,acc2); acc3 = mfma16(a30,b0,acc3);
    acc0 = mfma16(a01,b1,acc0); acc1 = mfma16(a11,b1,acc1);
    acc2 = mfma16(a21,b1,acc2); acc3 = mfma16(a31,b1,acc3);
  }
  #pragma unroll
  for(int r=0;r<4;r++){
    red[w][     lq*4+r][lm] = acc0[r];
    red[w][16 + lq*4+r][lm] = acc1[r];
    red[w][32 + lq*4+r][lm] = acc2[r];
    red[w][48 + lq*4+r][lm] = acc3[r];
  }
  __syncthreads();
  int m = tid>>2;
  #pragma unroll
  for(int j=0;j<4;j++){
    int c = (tid&3)*4 + j;
    float v = red[0][m][c]+red[1][m][c]+red[2][m][c]+red[3][m][c];
    gi[(size_t)m*3072 + blockIdx.x*16 + c] = v;
  }
}

// ---- 4: GRU elementwise -> hid f32 (output), hid_b bf16, a2_b[:, :1024] ----
__global__ void k_gru(const float* __restrict__ gi, const float* __restrict__ gh,
                      const float* __restrict__ bih, const float* __restrict__ bhh,
                      const float* __restrict__ h0, float* __restrict__ hid,
                      short* __restrict__ hid_b, short* __restrict__ a2_b){
  int t = blockIdx.x*256 + threadIdx.x;   // 16384
  int b = t>>8, j = (t&255)*4;
  const float* gib = gi + (size_t)b*3072 + j;
  const float* ghb = gh + (size_t)b*3072 + j;
  f4 h0v = *(const f4*)(h0 + (size_t)b*1024 + j);
  f4 hres; short4 hb;
  #pragma unroll
  for(int c=0;c<4;c++){
    float r = sigm(gib[c]      + bih[j+c]      + ghb[c]      + bhh[j+c]);
    float z = sigm(gib[1024+c] + bih[1024+j+c] + ghb[1024+c] + bhh[1024+j+c]);
    float n = tanhf(gib[2048+c] + bih[2048+j+c] + r*(ghb[2048+c] + bhh[2048+j+c]));
    float hv = ((const float*)&h0v)[c];
    float h = (1.0f - z)*n + z*hv;
    ((float*)&hres)[c] = h;
    ((short*)&hb)[c] = f2bf(h);
  }
  *(f4*)(hid + (size_t)b*1024 + j) = hres;
  *(short4*)(hid_b + (size_t)b*1024 + j) = hb;
  *(short4*)(a2_b + (size_t)b*2048 + j) = hb;
}

// ---- 5: blocks 0..511: flash attention chunks; blocks 512..575: W_write gemm ----
__launch_bounds__(256)
__global__ void k_flash(const float* __restrict__ enc, const float* __restrict__ hid,
                        float* __restrict__ part, float* __restrict__ ml,
                        const short* __restrict__ hid_b,
                        const float* __restrict__ Wwrite, const float* __restrict__ bwrite,
                        const float* __restrict__ emog, float* __restrict__ memo){
  __shared__ float red[4][64][20];
  int tid = threadIdx.x;
  int w = tid>>6, l = tid&63;
  if(blockIdx.x < 512){
    int b = blockIdx.x>>3, c = blockIdx.x&7;
    int chunk = c*4 + w;
    const float* hp = hid + (size_t)b*1024 + l*16;
    f4 q0 = *(const f4*)(hp), q1 = *(const f4*)(hp+4);
    f4 q2 = *(const f4*)(hp+8), q3 = *(const f4*)(hp+12);
    f4 cx0={0,0,0,0}, cx1={0,0,0,0}, cx2={0,0,0,0}, cx3={0,0,0,0};
    float mx = -1e30f, ls = 0.0f;
    int s0 = c*32 + w*8;
    for(int si=0; si<8; si++){
      const float* ep = enc + ((size_t)(s0+si)*64 + b)*1024 + l*16;
      f4 e0 = *(const f4*)(ep),   e1 = *(const f4*)(ep+4);
      f4 e2 = *(const f4*)(ep+8), e3 = *(const f4*)(ep+12);
      float d = e0.x*q0.x + e0.y*q0.y + e0.z*q0.z + e0.w*q0.w
              + e1.x*q1.x + e1.y*q1.y + e1.z*q1.z + e1.w*q1.w
              + e2.x*q2.x + e2.y*q2.y + e2.z*q2.z + e2.w*q2.w
              + e3.x*q3.x + e3.y*q3.y + e3.z*q3.z + e3.w*q3.w;
      d = wrsum(d);
      float mn = fmaxf(mx, d);
      float a = expf(mx - mn), p = expf(d - mn);
      ls = ls*a + p;
      cx0.x = cx0.x*a + p*e0.x; cx0.y = cx0.y*a + p*e0.y;
      cx0.z = cx0.z*a + p*e0.z; cx0.w = cx0.w*a + p*e0.w;
      cx1.x = cx1.x*a + p*e1.x; cx1.y = cx1.y*a + p*e1.y;
      cx1.z = cx1.z*a + p*e1.z; cx1.w = cx1.w*a + p*e1.w;
      cx2.x = cx2.x*a + p*e2.x; cx2.y = cx2.y*a + p*e2.y;
      cx2.z = cx2.z*a + p*e2.z; cx2.w = cx2.w*a + p*e2.w;
      cx3.x = cx3.x*a + p*e3.x; cx3.y = cx3.y*a + p*e3.y;
      cx3.z = cx3.z*a + p*e3.z; cx3.w = cx3.w*a + p*e3.w;
      mx = mn;
    }
    float* pp = part + ((size_t)b*32 + chunk)*1024 + l*16;
    *(f4*)(pp)    = cx0; *(f4*)(pp+4)  = cx1;
    *(f4*)(pp+8)  = cx2; *(f4*)(pp+12) = cx3;
    if(l==0){ ml[((size_t)b*32+chunk)*2] = mx; ml[((size_t)b*32+chunk)*2+1] = ls; }
  } else {
    int tile = blockIdx.x - 512;
    int lm = l&15, lq = l>>4;
    int ncol = tile*16 + lm;
    const float* wp = Wwrite + (size_t)ncol*1024 + lq*8;
    const short* ap = hid_b + lm*1024 + lq*8;
    int kbeg = w*256, kend = kbeg + 256;
    f32x4 acc0={0,0,0,0}, acc1={0,0,0,0}, acc2={0,0,0,0}, acc3={0,0,0,0};
    for(int k0=kbeg; k0<kend; k0+=64){
      f4 w0 = *(const f4*)(wp + k0);
      f4 w1 = *(const f4*)(wp + k0 + 4);
      f4 w2 = *(const f4*)(wp + k0 + 32);
      f4 w3 = *(const f4*)(wp + k0 + 36);
      bf16x8 a00 = *(const bf16x8*)(ap + k0);
      bf16x8 a01 = *(const bf16x8*)(ap + k0 + 32);
      bf16x8 a10 = *(const bf16x8*)(ap + 16*1024 + k0);
      bf16x8 a11 = *(const bf16x8*)(ap + 16*1024 + k0 + 32);
      bf16x8 a20 = *(const bf16x8*)(ap + 32*1024 + k0);
      bf16x8 a21 = *(const bf16x8*)(ap + 32*1024 + k0 + 32);
      bf16x8 a30 = *(const bf16x8*)(ap + 48*1024 + k0);
      bf16x8 a31 = *(const bf16x8*)(ap + 48*1024 + k0 + 32);
      bf16x8 b0 = pack8(w0,w1), b1 = pack8(w2,w3);
      acc0 = mfma16(a00,b0,acc0); acc1 = mfma16(a10,b0,acc1);
      acc2 = mfma16(a20,b0,acc2); acc3 = mfma16(a30,b0,acc3);
      acc0 = mfma16(a01,b1,acc0); acc1 = mfma16(a11,b1,acc1);
      acc2 = mfma16(a21,b1,acc2); acc3 = mfma16(a31,b1,acc3);
    }
    #pragma unroll
    for(int r=0;r<4;r++){
      red[w][     lq*4+r][lm] = acc0[r];
      red[w][16 + lq*4+r][lm] = acc1[r];
      red[w][32 + lq*4+r][lm] = acc2[r];
      red[w][48 + lq*4+r][lm] = acc3[r];
    }
    __syncthreads();
    int m = tid>>2;
    #pragma unroll
    for(int j=0;j<4;j++){
      int c = (tid&3)*4 + j;
      float v = red[0][m][c]+red[1][m][c]+red[2][m][c]+red[3][m][c];
      int n = tile*16 + c;
      memo[(size_t)m*1024 + n] = sigm(v + bwrite[n]) * emog[(size_t)m*1024 + n];
    }
  }
}

// ---- 6: merge 32 chunk partials -> context f32 (output) + a2_b[:, 1024:] bf16 ----
__global__ void k_ctxr(const float* __restrict__ part, const float* __restrict__ ml,
                       float* __restrict__ ctxo, short* __restrict__ a2_b){
  int b = blockIdx.x; int t = threadIdx.x;
  __shared__ float sscale[32];
  if(t < 64){
    float mc = (t<32) ? ml[((size_t)b*32+t)*2]   : -1e30f;
    float lc = (t<32) ? ml[((size_t)b*32+t)*2+1] : 0.0f;
    float M = wrmax(mc);
    float L = wrsum(lc * expf(mc - M));
    if(t<32) sscale[t] = expf(mc - M) / L;
  }
  __syncthreads();
  int h = t*4;
  f4 acc = {0,0,0,0};
  for(int c=0;c<32;c++){
    f4 p = *(const f4*)(part + ((size_t)b*32 + c)*1024 + h);
    float s = sscale[c];
    acc.x += s*p.x; acc.y += s*p.y; acc.z += s*p.z; acc.w += s*p.w;
  }
  *(f4*)(ctxo + (size_t)b*1024 + h) = acc;
  *(short4*)(a2_b + (size_t)b*2048 + 1024 + h) =
      make_short4(f2bf(acc.x),f2bf(acc.y),f2bf(acc.z),f2bf(acc.w));
}

// ---- 7: concat_out = tanh(a2 @ W_concat^T + b) -> cc_b bf16 ----
__launch_bounds__(256)
__global__ void k_cc(const short* __restrict__ a2_b, const float* __restrict__ Wc,
                     const float* __restrict__ bc, short* __restrict__ cc_b){
  __shared__ float red[4][64][20];
  int tid = threadIdx.x;
  int w = tid>>6, l = tid&63, lm = l&15, lq = l>>4;
  int ncol = blockIdx.x*16 + lm;
  const float* wp = Wc + (size_t)ncol*2048 + lq*8;
  const short* ap = a2_b + lm*2048 + lq*8;
  int kbeg = w*512, kend = kbeg + 512;
  f32x4 acc0={0,0,0,0}, acc1={0,0,0,0}, acc2={0,0,0,0}, acc3={0,0,0,0};
  for(int k0=kbeg; k0<kend; k0+=64){
    f4 w0 = *(const f4*)(wp + k0);
    f4 w1 = *(const f4*)(wp + k0 + 4);
    f4 w2 = *(const f4*)(wp + k0 + 32);
    f4 w3 = *(const f4*)(wp + k0 + 36);
    bf16x8 a00 = *(const bf16x8*)(ap + k0);
    bf16x8 a01 = *(const bf16x8*)(ap + k0 + 32);
    bf16x8 a10 = *(const bf16x8*)(ap + 16*2048 + k0);
    bf16x8 a11 = *(const bf16x8*)(ap + 16*2048 + k0 + 32);
    bf16x8 a20 = *(const bf16x8*)(ap + 32*2048 + k0);
    bf16x8 a21 = *(const bf16x8*)(ap + 32*2048 + k0 + 32);
    bf16x8 a30 = *(const bf16x8*)(ap + 48*2048 + k0);
    bf16x8 a31 = *(const bf16x8*)(ap + 48*2048 + k0 + 32);
    bf16x8 b0 = pack8(w0,w1), b1 = pack8(w2,w3);
    acc0 = mfma16(a00,b0,acc0); acc1 = mfma16(a10,b0,acc1);
    acc2 = mfma16(a20,b0,acc2); acc3 = mfma16(a30,b0,acc3);
    acc0 = mfma16(a01,b1,acc0); acc1 = mfma16(a11,b1,acc1);
    acc2 = mfma16(a21,b1,acc2); acc3 = mfma16(a31,b1,acc3);
  }
  #pragma unroll
  for(int r=0;r<4;r++){
    red[w][     lq*4+r][lm] = acc0[r];
    red[w][16 + lq*4+r][lm] = acc1[r];
    red[w][32 + lq*4+r][lm] = acc2[r];
    red[w][48 + lq*4+r][lm] = acc3[r];
  }
  __syncthreads();
  int m = tid>>2;
  #pragma unroll
  for(int j=0;j<4;j++){
    int c = (tid&3)*4 + j;
    float v = red[0][m][c]+red[1][m][c]+red[2][m][c]+red[3][m][c];
    int n = blockIdx.x*16 + c;
    cc_b[(size_t)m*1024 + n] = f2bf(tanhf(v + bc[n]));
  }
}

// ---- 8: logits = cc @ W_out^T + b_out (direct MFMA, no LDS/barriers) ----
__launch_bounds__(256)
__global__ void k_out(const short* __restrict__ A, const float* __restrict__ Wm,
                      const float* __restrict__ bias, float* __restrict__ outf){
  int tid = threadIdx.x;
  int w = tid>>6, l = tid&63;
  int lm = l&15, lq = l>>4;
  int ncol = blockIdx.x*64 + w*16 + lm;
  int nrow = ncol < V ? ncol : V-1;
  const float* wp = Wm + (size_t)nrow*1024 + lq*8;
  const short* ap = A + lm*1024 + lq*8;
  f32x4 acc0={0,0,0,0}, acc1={0,0,0,0}, acc2={0,0,0,0}, acc3={0,0,0,0};
  for(int k0=0; k0<1024; k0+=64){
    f4 w0 = *(const f4*)(wp + k0);
    f4 w1 = *(const f4*)(wp + k0 + 4);
    f4 w2 = *(const f4*)(wp + k0 + 32);
    f4 w3 = *(const f4*)(wp + k0 + 36);
    bf16x8 a00 = *(const bf16x8*)(ap + k0);
    bf16x8 a01 = *(const bf16x8*)(ap + k0 + 32);
    bf16x8 a10 = *(const bf16x8*)(ap + 16*1024 + k0);
    bf16x8 a11 = *(const bf16x8*)(ap + 16*1024 + k0 + 32);
    bf16x8 a20 = *(const bf16x8*)(ap + 32*1024 + k0);
    bf16x8 a21 = *(const bf16x8*)(ap + 32*1024 + k0 + 32);
    bf16x8 a30 = *(const bf16x8*)(ap + 48*1024 + k0);
    bf16x8 a31 = *(const bf16x8*)(ap + 48*1024 + k0 + 32);
    bf16x8 b0 = pack8(w0,w1), b1 = pack8(w2,w3);
    acc0 = mfma16(a00,b0,acc0); acc1 = mfma16(a10,b0,acc1);
    acc2 = mfma16(a20,b0,acc2); acc3 = mfma16(a30,b0,acc3);
    acc0 = mfma16(a01,b1,acc0); acc1 = mfma16(a11,b1,acc1);
    acc2 = mfma16(a21,b1,acc2); acc3 = mfma16(a31,b1,acc3);
  }
  if(ncol < V){
    float bv = bias[ncol];
    #pragma unroll
    for(int r=0;r<4;r++){
      int m0 = lq*4 + r;
      outf[(size_t)(m0     )*V + ncol] = acc0[r] + bv;
      outf[(size_t)(m0 + 16)*V + ncol] = acc1[r] + bv;
      outf[(size_t)(m0 + 32)*V + ncol] = acc2[r] + bv;
      outf[(size_t)(m0 + 48)*V + ncol] = acc3[r] + bv;
    }
  }
}

// ---- 9: single-pass row stats (alpha-dot + online masked/unmasked max,sum) ----
__global__ void k_rowpass(const float* __restrict__ logits, const float* __restrict__ wal,
                          const int* __restrict__ mem, float* __restrict__ stats){
  int b = blockIdx.x, t = threadIdx.x;
  const float* lp = logits + (size_t)b*V;
  float dot=0.0f, me=-1e30f, se=0.0f, mg=-1e30f, sg=0.0f;
  for(int v=t; v<V; v+=256){
    float l = lp[v];
    dot += l*wal[v];
    if(mem[v]==1){
      if(l<=me) se += expf(l-me); else { se = se*expf(me-l) + 1.0f; me = l; }
    } else {
      if(l<=mg) sg += expf(l-mg); else { sg = sg*expf(mg-l) + 1.0f; mg = l; }
    }
  }
  #pragma unroll
  for(int o=32;o;o>>=1){
    float me2=__shfl_xor(me,o), se2=__shfl_xor(se,o);
    float m = fmaxf(me,me2); se = se*expf(me-m) + se2*expf(me2-m); me = m;
    float mg2=__shfl_xor(mg,o), sg2=__shfl_xor(sg,o);
    float m2 = fmaxf(mg,mg2); sg = sg*expf(mg-m2) + sg2*expf(mg2-m2); mg = m2;
    dot += __shfl_xor(dot,o);
  }
  __shared__ float sm[4][5];
  int wv = t>>6;
  if((t&63)==0){ sm[wv][0]=dot; sm[wv][1]=me; sm[wv][2]=se; sm[wv][3]=mg; sm[wv][4]=sg; }
  __syncthreads();
  if(t==0){
    float D=0, M=-1e30f, S=0, M2=-1e30f, S2=0;
    for(int i=0;i<4;i++){
      D += sm[i][0];
      float m = fmaxf(M, sm[i][1]); S  = S*expf(M-m)  + sm[i][2]*expf(sm[i][1]-m);  M = m;
      float n = fmaxf(M2,sm[i][3]); S2 = S2*expf(M2-n)+ sm[i][4]*expf(sm[i][3]-n); M2 = n;
    }
    stats[b*8+0]=D; stats[b*8+1]=M; stats[b*8+2]=M2; stats[b*8+3]=S; stats[b*8+4]=S2;
  }
}

// ---- 10: dual gated softmax in-place ----
__global__ void k_final(float* __restrict__ logits, const int* __restrict__ mem,
                        const float* __restrict__ stats, const float* __restrict__ balpha){
  int v = blockIdx.x*256 + threadIdx.x;
  int b = blockIdx.y;
  if(v >= V) return;
  float dot = stats[b*8+0], me = stats[b*8+1], mg = stats[b*8+2];
  float se = stats[b*8+3],  sg = stats[b*8+4];
  float g = sigm(dot + balpha[0]);
  float l = logits[(size_t)b*V + v];
  float o = (mem[v]==1) ? (expf(l-me)/se * g) : (expf(l-mg)/sg * (1.0f-g));
  logits[(size_t)b*V + v] = o;
}

extern "C" void kernel_launch(void* const* d_in, const int* in_sizes, int n_in,
                              void* d_out, int out_size, void* d_ws, size_t ws_size,
                              hipStream_t stream){
  const int*   istep   = (const int*)d_in[0];
  const int*   iemo    = (const int*)d_in[1];
  const float* lasth   = (const float*)d_in[2];
  const float* ictx    = (const float*)d_in[3];
  const float* enc     = (const float*)d_in[4];
  const int*   emem    = (const int*)d_in[5];
  const float* emb     = (const float*)d_in[6];
  const float* eemb    = (const float*)d_in[7];
  const float* W_read  = (const float*)d_in[8];
  const float* b_read  = (const float*)d_in[9];
  const float* W_write = (const float*)d_in[10];
  const float* b_write = (const float*)d_in[11];
  const float* W_ih    = (const float*)d_in[12];
  const float* W_hh    = (const float*)d_in[13];
  const float* b_ih    = (const float*)d_in[14];
  const float* b_hh    = (const float*)d_in[15];
  const float* W_concat= (const float*)d_in[16];
  const float* b_concat= (const float*)d_in[17];
  const float* W_out   = (const float*)d_in[18];
  const float* b_out   = (const float*)d_in[19];
  const float* W_alpha = (const float*)d_in[20];
  const float* b_alpha = (const float*)d_in[21];

  short* X_b  = (short*)d_ws;                           // 64x4096 bf16
  float* emog = (float*)((char*)d_ws + 524288);         // 64x1024
  float* gi   = emog + 65536;                           // 64x3072
  float* gh   = gi + 196608;                            // 64x3072
  float* part = gh + 196608;                            // 64x32x1024
  float* ml   = part + 2097152;                         // 64x32x2
  float* stats= ml + 4096;                              // 512
  short* hid_b= (short*)(stats + 512);                  // 64x1024 bf16
  short* a2_b = hid_b + 65536;                          // 64x2048 bf16
  short* cc_b = a2_b + 131072;                          // 64x1024 bf16

  float* out0 = (float*)d_out;          // [64][V]
  float* hid  = out0 + (size_t)B*V;     // [64][1024] (output: hidden)
  float* memo = hid + 65536;            // [64][1024] (output: new_M_emo)
  float* ctxo = memo + 65536;           // [64][1024] (output: context)

  k_build<<<64,256,0,stream>>>(istep, lasth, ictx, emb, X_b);
  // 64 W_read tiles + 192 W_hh tiles (gh is [64,3072] -> 192 column tiles)
  k_pre  <<<256,256,0,stream>>>(iemo, X_b, eemb, W_read, b_read, W_hh, emog, X_b, gh);
  k_gi   <<<192,256,0,stream>>>(X_b, W_ih, gi);
  k_gru  <<<64,256,0,stream>>>(gi, gh, b_ih, b_hh, lasth, hid, hid_b, a2_b);
  k_flash<<<576,256,0,stream>>>(enc, hid, part, ml, hid_b, W_write, b_write, emog, memo);
  k_ctxr <<<64,256,0,stream>>>(part, ml, ctxo, a2_b);
  k_cc   <<<64,256,0,stream>>>(a2_b, W_concat, b_concat, cc_b);
  k_out  <<<786,256,0,stream>>>(cc_b, W_out, b_out, out0);
  k_rowpass<<<64,256,0,stream>>>(out0, W_alpha, emem, stats);
  k_final<<<dim3(197,64),256,0,stream>>>(out0, emem, stats, b_alpha);
}

// Round 7
// 226.916 us; speedup vs baseline: 1.8281x; 1.3271x over previous
//
#include <hip/hip_runtime.h>
#include <hip/hip_bf16.h>
#include <math.h>

#define B 64
#define H 1024
#define SEQ 256
#define V 50257
#define NBLK 786   // ceil(V/64)

typedef float4 f4;
typedef __attribute__((ext_vector_type(4))) float f32x4;
typedef __attribute__((ext_vector_type(8))) short bf16x8;

__device__ inline float sigm(float x){ return 1.0f/(1.0f+expf(-x)); }
__device__ inline short f2bf(float x){
  __hip_bfloat16 h = __float2bfloat16(x);
  union { __hip_bfloat16 h; short s; } u; u.h = h; return u.s;
}
__device__ inline short2 cvt2(float x, float y){
  __hip_bfloat162 h = __float22bfloat162_rn(float2{x, y});
  union { __hip_bfloat162 h; short2 s; } u; u.h = h; return u.s;
}
__device__ inline bf16x8 pack8(f4 lo, f4 hi){
  union { bf16x8 v; short2 s[4]; } u;
  u.s[0]=cvt2(lo.x,lo.y); u.s[1]=cvt2(lo.z,lo.w);
  u.s[2]=cvt2(hi.x,hi.y); u.s[3]=cvt2(hi.z,hi.w);
  return u.v;
}
__device__ inline float wrsum(float v){
  #pragma unroll
  for(int o=32;o;o>>=1) v += __shfl_xor(v,o);
  return v;
}
__device__ inline float wrmax(float v){
  #pragma unroll
  for(int o=32;o;o>>=1) v = fmaxf(v,__shfl_xor(v,o));
  return v;
}
__device__ inline f32x4 mfma16(bf16x8 a, bf16x8 b, f32x4 c){
  return __builtin_amdgcn_mfma_f32_16x16x32_bf16(a,b,c,0,0,0);
}

// ---- 1: build X_b[:, :3072] = bf16[emb(iw) | lasth | ictx] ----
__global__ void k_build(const int* __restrict__ istep,
                        const float* __restrict__ lasth, const float* __restrict__ ictx,
                        const float* __restrict__ emb, short* __restrict__ X_b){
  int b = blockIdx.x; int h = threadIdx.x*4;
  int iw = istep[b];
  f4 lw = *(const f4*)(emb  + (size_t)iw*H + h);
  f4 hs = *(const f4*)(lasth + (size_t)b*H + h);
  f4 cv = *(const f4*)(ictx + (size_t)b*H + h);
  short* xb = X_b + (size_t)b*4096;
  *(short4*)(xb +        h) = make_short4(f2bf(lw.x),f2bf(lw.y),f2bf(lw.z),f2bf(lw.w));
  *(short4*)(xb + 1024 + h) = make_short4(f2bf(hs.x),f2bf(hs.y),f2bf(hs.z),f2bf(hs.w));
  *(short4*)(xb + 2048 + h) = make_short4(f2bf(cv.x),f2bf(cv.y),f2bf(cv.z),f2bf(cv.w));
}

// ---- 2: blocks 0..63: W_read gemm + sigmoid*eemb -> emog f32 + X_b[:,3072:] bf16
//         blocks 64..255: W_hh gemm (192 tiles) -> gh raw f32 ----
__launch_bounds__(256)
__global__ void k_pre(const int* __restrict__ iemo, const short* __restrict__ X_b,
                      const float* __restrict__ eemb,
                      const float* __restrict__ Wread, const float* __restrict__ bread,
                      const float* __restrict__ Whh,
                      float* __restrict__ emog, short* __restrict__ X_b_w,
                      float* __restrict__ gh){
  __shared__ float red[4][64][20];
  int tid = threadIdx.x;
  int w = tid>>6, l = tid&63, lm = l&15, lq = l>>4;
  f32x4 acc0={0,0,0,0}, acc1={0,0,0,0}, acc2={0,0,0,0}, acc3={0,0,0,0};
  int readmode = (blockIdx.x < 64);
  int tile = readmode ? blockIdx.x : (blockIdx.x - 64);
  int ncol = tile*16 + lm;
  const float* wp = readmode ? (Wread + (size_t)ncol*3072 + lq*8)
                             : (Whh   + (size_t)ncol*1024 + lq*8);
  const short* ap = readmode ? (X_b + lm*4096 + lq*8)
                             : (X_b + 1024 + lm*4096 + lq*8);
  int kbeg = readmode ? w*768 : w*256;
  int kend = readmode ? (kbeg + 768) : (kbeg + 256);
  for(int k0=kbeg; k0<kend; k0+=64){
    f4 w0 = *(const f4*)(wp + k0);
    f4 w1 = *(const f4*)(wp + k0 + 4);
    f4 w2 = *(const f4*)(wp + k0 + 32);
    f4 w3 = *(const f4*)(wp + k0 + 36);
    bf16x8 a00 = *(const bf16x8*)(ap + k0);
    bf16x8 a01 = *(const bf16x8*)(ap + k0 + 32);
    bf16x8 a10 = *(const bf16x8*)(ap + 16*4096 + k0);
    bf16x8 a11 = *(const bf16x8*)(ap + 16*4096 + k0 + 32);
    bf16x8 a20 = *(const bf16x8*)(ap + 32*4096 + k0);
    bf16x8 a21 = *(const bf16x8*)(ap + 32*4096 + k0 + 32);
    bf16x8 a30 = *(const bf16x8*)(ap + 48*4096 + k0);
    bf16x8 a31 = *(const bf16x8*)(ap + 48*4096 + k0 + 32);
    bf16x8 b0 = pack8(w0,w1), b1 = pack8(w2,w3);
    acc0 = mfma16(a00,b0,acc0); acc1 = mfma16(a10,b0,acc1);
    acc2 = mfma16(a20,b0,acc2); acc3 = mfma16(a30,b0,acc3);
    acc0 = mfma16(a01,b1,acc0); acc1 = mfma16(a11,b1,acc1);
    acc2 = mfma16(a21,b1,acc2); acc3 = mfma16(a31,b1,acc3);
  }
  #pragma unroll
  for(int r=0;r<4;r++){
    red[w][     lq*4+r][lm] = acc0[r];
    red[w][16 + lq*4+r][lm] = acc1[r];
    red[w][32 + lq*4+r][lm] = acc2[r];
    red[w][48 + lq*4+r][lm] = acc3[r];
  }
  __syncthreads();
  int m = tid>>2;
  if(readmode){
    int ie = iemo[m];
    #pragma unroll
    for(int j=0;j<4;j++){
      int c = (tid&3)*4 + j;
      float v = red[0][m][c]+red[1][m][c]+red[2][m][c]+red[3][m][c];
      int n = tile*16 + c;
      float s = sigm(v + bread[n]);
      float eg = s * eemb[(size_t)ie*1024 + n];
      emog[(size_t)m*1024 + n] = eg;
      X_b_w[(size_t)m*4096 + 3072 + n] = f2bf(eg);
    }
  } else {
    #pragma unroll
    for(int j=0;j<4;j++){
      int c = (tid&3)*4 + j;
      float v = red[0][m][c]+red[1][m][c]+red[2][m][c]+red[3][m][c];
      gh[(size_t)m*3072 + tile*16 + c] = v;
    }
  }
}

// ---- 3: gi partials = X @ W_ih^T, 2-way K-split (grid (192,2)) ----
__launch_bounds__(256)
__global__ void k_gi(const short* __restrict__ X_b, const float* __restrict__ Wih,
                     float* __restrict__ gp){
  __shared__ float red[4][64][20];
  int tid = threadIdx.x;
  int w = tid>>6, l = tid&63, lm = l&15, lq = l>>4;
  int half = blockIdx.y;
  int ncol = blockIdx.x*16 + lm;
  const float* wp = Wih + (size_t)ncol*4096 + lq*8;
  const short* ap = X_b + lm*4096 + lq*8;
  int kbeg = half*2048 + w*512, kend = kbeg + 512;
  f32x4 acc0={0,0,0,0}, acc1={0,0,0,0}, acc2={0,0,0,0}, acc3={0,0,0,0};
  for(int k0=kbeg; k0<kend; k0+=64){
    f4 w0 = *(const f4*)(wp + k0);
    f4 w1 = *(const f4*)(wp + k0 + 4);
    f4 w2 = *(const f4*)(wp + k0 + 32);
    f4 w3 = *(const f4*)(wp + k0 + 36);
    bf16x8 a00 = *(const bf16x8*)(ap + k0);
    bf16x8 a01 = *(const bf16x8*)(ap + k0 + 32);
    bf16x8 a10 = *(const bf16x8*)(ap + 16*4096 + k0);
    bf16x8 a11 = *(const bf16x8*)(ap + 16*4096 + k0 + 32);
    bf16x8 a20 = *(const bf16x8*)(ap + 32*4096 + k0);
    bf16x8 a21 = *(const bf16x8*)(ap + 32*4096 + k0 + 32);
    bf16x8 a30 = *(const bf16x8*)(ap + 48*4096 + k0);
    bf16x8 a31 = *(const bf16x8*)(ap + 48*4096 + k0 + 32);
    bf16x8 b0 = pack8(w0,w1), b1 = pack8(w2,w3);
    acc0 = mfma16(a00,b0,acc0); acc1 = mfma16(a10,b0,acc1);
    acc2 = mfma16(a20,b0,acc2); acc3 = mfma16(a30,b0,acc3);
    acc0 = mfma16(a01,b1,acc0); acc1 = mfma16(a11,b1,acc1);
    acc2 = mfma16(a21,b1,acc2); acc3 = mfma16(a31,b1,acc3);
  }
  #pragma unroll
  for(int r=0;r<4;r++){
    red[w][     lq*4+r][lm] = acc0[r];
    red[w][16 + lq*4+r][lm] = acc1[r];
    red[w][32 + lq*4+r][lm] = acc2[r];
    red[w][48 + lq*4+r][lm] = acc3[r];
  }
  __syncthreads();
  int m = tid>>2;
  #pragma unroll
  for(int j=0;j<4;j++){
    int c = (tid&3)*4 + j;
    float v = red[0][m][c]+red[1][m][c]+red[2][m][c]+red[3][m][c];
    gp[(size_t)(half*64+m)*3072 + blockIdx.x*16 + c] = v;
  }
}

// ---- 4: GRU elementwise (sums 2 gi partials + biases) ----
__global__ void k_gru(const float* __restrict__ gp, const float* __restrict__ gh,
                      const float* __restrict__ bih, const float* __restrict__ bhh,
                      const float* __restrict__ h0, float* __restrict__ hid,
                      short* __restrict__ hid_b, short* __restrict__ a2_b){
  int t = blockIdx.x*256 + threadIdx.x;   // 16384
  int b = t>>8, j = (t&255)*4;
  const float* gi0 = gp + (size_t)b*3072 + j;
  const float* gi1 = gp + (size_t)(64+b)*3072 + j;
  const float* ghb = gh + (size_t)b*3072 + j;
  f4 h0v = *(const f4*)(h0 + (size_t)b*1024 + j);
  f4 hres; short4 hb;
  #pragma unroll
  for(int c=0;c<4;c++){
    float r = sigm(gi0[c]      + gi1[c]      + bih[j+c]      + ghb[c]      + bhh[j+c]);
    float z = sigm(gi0[1024+c] + gi1[1024+c] + bih[1024+j+c] + ghb[1024+c] + bhh[1024+j+c]);
    float n = tanhf(gi0[2048+c] + gi1[2048+c] + bih[2048+j+c] + r*(ghb[2048+c] + bhh[2048+j+c]));
    float hv = ((const float*)&h0v)[c];
    float h = (1.0f - z)*n + z*hv;
    ((float*)&hres)[c] = h;
    ((short*)&hb)[c] = f2bf(h);
  }
  *(f4*)(hid + (size_t)b*1024 + j) = hres;
  *(short4*)(hid_b + (size_t)b*1024 + j) = hb;
  *(short4*)(a2_b + (size_t)b*2048 + j) = hb;
}

// ---- 5: blocks 0..511: flash attention chunks; blocks 512..575: W_write gemm ----
__launch_bounds__(256)
__global__ void k_flash(const float* __restrict__ enc, const float* __restrict__ hid,
                        float* __restrict__ part, float* __restrict__ ml,
                        const short* __restrict__ hid_b,
                        const float* __restrict__ Wwrite, const float* __restrict__ bwrite,
                        const float* __restrict__ emog, float* __restrict__ memo){
  __shared__ float red[4][64][20];
  int tid = threadIdx.x;
  int w = tid>>6, l = tid&63;
  if(blockIdx.x < 512){
    int b = blockIdx.x>>3, c = blockIdx.x&7;
    int chunk = c*4 + w;
    const float* hp = hid + (size_t)b*1024 + l*16;
    f4 q0 = *(const f4*)(hp), q1 = *(const f4*)(hp+4);
    f4 q2 = *(const f4*)(hp+8), q3 = *(const f4*)(hp+12);
    f4 cx0={0,0,0,0}, cx1={0,0,0,0}, cx2={0,0,0,0}, cx3={0,0,0,0};
    float mx = -1e30f, ls = 0.0f;
    int s0 = c*32 + w*8;
    for(int si=0; si<8; si++){
      const float* ep = enc + ((size_t)(s0+si)*64 + b)*1024 + l*16;
      f4 e0 = *(const f4*)(ep),   e1 = *(const f4*)(ep+4);
      f4 e2 = *(const f4*)(ep+8), e3 = *(const f4*)(ep+12);
      float d = e0.x*q0.x + e0.y*q0.y + e0.z*q0.z + e0.w*q0.w
              + e1.x*q1.x + e1.y*q1.y + e1.z*q1.z + e1.w*q1.w
              + e2.x*q2.x + e2.y*q2.y + e2.z*q2.z + e2.w*q2.w
              + e3.x*q3.x + e3.y*q3.y + e3.z*q3.z + e3.w*q3.w;
      d = wrsum(d);
      float mn = fmaxf(mx, d);
      float a = expf(mx - mn), p = expf(d - mn);
      ls = ls*a + p;
      cx0.x = cx0.x*a + p*e0.x; cx0.y = cx0.y*a + p*e0.y;
      cx0.z = cx0.z*a + p*e0.z; cx0.w = cx0.w*a + p*e0.w;
      cx1.x = cx1.x*a + p*e1.x; cx1.y = cx1.y*a + p*e1.y;
      cx1.z = cx1.z*a + p*e1.z; cx1.w = cx1.w*a + p*e1.w;
      cx2.x = cx2.x*a + p*e2.x; cx2.y = cx2.y*a + p*e2.y;
      cx2.z = cx2.z*a + p*e2.z; cx2.w = cx2.w*a + p*e2.w;
      cx3.x = cx3.x*a + p*e3.x; cx3.y = cx3.y*a + p*e3.y;
      cx3.z = cx3.z*a + p*e3.z; cx3.w = cx3.w*a + p*e3.w;
      mx = mn;
    }
    float* pp = part + ((size_t)b*32 + chunk)*1024 + l*16;
    *(f4*)(pp)    = cx0; *(f4*)(pp+4)  = cx1;
    *(f4*)(pp+8)  = cx2; *(f4*)(pp+12) = cx3;
    if(l==0){ ml[((size_t)b*32+chunk)*2] = mx; ml[((size_t)b*32+chunk)*2+1] = ls; }
  } else {
    int tile = blockIdx.x - 512;
    int lm = l&15, lq = l>>4;
    int ncol = tile*16 + lm;
    const float* wp = Wwrite + (size_t)ncol*1024 + lq*8;
    const short* ap = hid_b + lm*1024 + lq*8;
    int kbeg = w*256, kend = kbeg + 256;
    f32x4 acc0={0,0,0,0}, acc1={0,0,0,0}, acc2={0,0,0,0}, acc3={0,0,0,0};
    for(int k0=kbeg; k0<kend; k0+=64){
      f4 w0 = *(const f4*)(wp + k0);
      f4 w1 = *(const f4*)(wp + k0 + 4);
      f4 w2 = *(const f4*)(wp + k0 + 32);
      f4 w3 = *(const f4*)(wp + k0 + 36);
      bf16x8 a00 = *(const bf16x8*)(ap + k0);
      bf16x8 a01 = *(const bf16x8*)(ap + k0 + 32);
      bf16x8 a10 = *(const bf16x8*)(ap + 16*1024 + k0);
      bf16x8 a11 = *(const bf16x8*)(ap + 16*1024 + k0 + 32);
      bf16x8 a20 = *(const bf16x8*)(ap + 32*1024 + k0);
      bf16x8 a21 = *(const bf16x8*)(ap + 32*1024 + k0 + 32);
      bf16x8 a30 = *(const bf16x8*)(ap + 48*1024 + k0);
      bf16x8 a31 = *(const bf16x8*)(ap + 48*1024 + k0 + 32);
      bf16x8 b0 = pack8(w0,w1), b1 = pack8(w2,w3);
      acc0 = mfma16(a00,b0,acc0); acc1 = mfma16(a10,b0,acc1);
      acc2 = mfma16(a20,b0,acc2); acc3 = mfma16(a30,b0,acc3);
      acc0 = mfma16(a01,b1,acc0); acc1 = mfma16(a11,b1,acc1);
      acc2 = mfma16(a21,b1,acc2); acc3 = mfma16(a31,b1,acc3);
    }
    #pragma unroll
    for(int r=0;r<4;r++){
      red[w][     lq*4+r][lm] = acc0[r];
      red[w][16 + lq*4+r][lm] = acc1[r];
      red[w][32 + lq*4+r][lm] = acc2[r];
      red[w][48 + lq*4+r][lm] = acc3[r];
    }
    __syncthreads();
    int m = tid>>2;
    #pragma unroll
    for(int j=0;j<4;j++){
      int c = (tid&3)*4 + j;
      float v = red[0][m][c]+red[1][m][c]+red[2][m][c]+red[3][m][c];
      int n = tile*16 + c;
      memo[(size_t)m*1024 + n] = sigm(v + bwrite[n]) * emog[(size_t)m*1024 + n];
    }
  }
}

// ---- 6: merge 32 chunk partials -> context f32 (output) + a2_b[:, 1024:] bf16 ----
__global__ void k_ctxr(const float* __restrict__ part, const float* __restrict__ ml,
                       float* __restrict__ ctxo, short* __restrict__ a2_b){
  int b = blockIdx.x; int t = threadIdx.x;
  __shared__ float sscale[32];
  if(t < 64){
    float mc = (t<32) ? ml[((size_t)b*32+t)*2]   : -1e30f;
    float lc = (t<32) ? ml[((size_t)b*32+t)*2+1] : 0.0f;
    float M = wrmax(mc);
    float L = wrsum(lc * expf(mc - M));
    if(t<32) sscale[t] = expf(mc - M) / L;
  }
  __syncthreads();
  int h = t*4;
  f4 acc = {0,0,0,0};
  for(int c=0;c<32;c++){
    f4 p = *(const f4*)(part + ((size_t)b*32 + c)*1024 + h);
    float s = sscale[c];
    acc.x += s*p.x; acc.y += s*p.y; acc.z += s*p.z; acc.w += s*p.w;
  }
  *(f4*)(ctxo + (size_t)b*1024 + h) = acc;
  *(short4*)(a2_b + (size_t)b*2048 + 1024 + h) =
      make_short4(f2bf(acc.x),f2bf(acc.y),f2bf(acc.z),f2bf(acc.w));
}

// ---- 7: concat_out = tanh(a2 @ W_concat^T + b) -> cc_b bf16 ----
__launch_bounds__(256)
__global__ void k_cc(const short* __restrict__ a2_b, const float* __restrict__ Wc,
                     const float* __restrict__ bc, short* __restrict__ cc_b){
  __shared__ float red[4][64][20];
  int tid = threadIdx.x;
  int w = tid>>6, l = tid&63, lm = l&15, lq = l>>4;
  int ncol = blockIdx.x*16 + lm;
  const float* wp = Wc + (size_t)ncol*2048 + lq*8;
  const short* ap = a2_b + lm*2048 + lq*8;
  int kbeg = w*512, kend = kbeg + 512;
  f32x4 acc0={0,0,0,0}, acc1={0,0,0,0}, acc2={0,0,0,0}, acc3={0,0,0,0};
  for(int k0=kbeg; k0<kend; k0+=64){
    f4 w0 = *(const f4*)(wp + k0);
    f4 w1 = *(const f4*)(wp + k0 + 4);
    f4 w2 = *(const f4*)(wp + k0 + 32);
    f4 w3 = *(const f4*)(wp + k0 + 36);
    bf16x8 a00 = *(const bf16x8*)(ap + k0);
    bf16x8 a01 = *(const bf16x8*)(ap + k0 + 32);
    bf16x8 a10 = *(const bf16x8*)(ap + 16*2048 + k0);
    bf16x8 a11 = *(const bf16x8*)(ap + 16*2048 + k0 + 32);
    bf16x8 a20 = *(const bf16x8*)(ap + 32*2048 + k0);
    bf16x8 a21 = *(const bf16x8*)(ap + 32*2048 + k0 + 32);
    bf16x8 a30 = *(const bf16x8*)(ap + 48*2048 + k0);
    bf16x8 a31 = *(const bf16x8*)(ap + 48*2048 + k0 + 32);
    bf16x8 b0 = pack8(w0,w1), b1 = pack8(w2,w3);
    acc0 = mfma16(a00,b0,acc0); acc1 = mfma16(a10,b0,acc1);
    acc2 = mfma16(a20,b0,acc2); acc3 = mfma16(a30,b0,acc3);
    acc0 = mfma16(a01,b1,acc0); acc1 = mfma16(a11,b1,acc1);
    acc2 = mfma16(a21,b1,acc2); acc3 = mfma16(a31,b1,acc3);
  }
  #pragma unroll
  for(int r=0;r<4;r++){
    red[w][     lq*4+r][lm] = acc0[r];
    red[w][16 + lq*4+r][lm] = acc1[r];
    red[w][32 + lq*4+r][lm] = acc2[r];
    red[w][48 + lq*4+r][lm] = acc3[r];
  }
  __syncthreads();
  int m = tid>>2;
  #pragma unroll
  for(int j=0;j<4;j++){
    int c = (tid&3)*4 + j;
    float v = red[0][m][c]+red[1][m][c]+red[2][m][c]+red[3][m][c];
    int n = blockIdx.x*16 + c;
    cc_b[(size_t)m*1024 + n] = f2bf(tanhf(v + bc[n]));
  }
}

// ---- 8: logits = cc @ W_out^T + b_out, 512 threads, 2-way K-split,
//         fused per-block row stats (dot, masked/unmasked online max+expsum) ----
__launch_bounds__(512)
__global__ void k_out(const short* __restrict__ A, const float* __restrict__ Wm,
                      const float* __restrict__ bias, const float* __restrict__ wal,
                      const int* __restrict__ mem,
                      float* __restrict__ outf, float* __restrict__ pstat){
  __shared__ float red[4][64][20];   // K-combine buffer (per col-group)
  __shared__ float sst[4][64][6];    // per col-group per-row stats
  int tid = threadIdx.x;
  int w = tid>>6, l = tid&63;
  int lm = l&15, lq = l>>4;
  int cg = w&3, half = w>>2;
  int ncol = blockIdx.x*64 + cg*16 + lm;
  int nrow = ncol < V ? ncol : V-1;
  const float* wp = Wm + (size_t)nrow*1024 + lq*8;
  const short* ap = A + lm*1024 + lq*8;
  int kbeg = half*512, kend = kbeg + 512;
  f32x4 acc0={0,0,0,0}, acc1={0,0,0,0}, acc2={0,0,0,0}, acc3={0,0,0,0};
  for(int k0=kbeg; k0<kend; k0+=64){
    f4 w0 = *(const f4*)(wp + k0);
    f4 w1 = *(const f4*)(wp + k0 + 4);
    f4 w2 = *(const f4*)(wp + k0 + 32);
    f4 w3 = *(const f4*)(wp + k0 + 36);
    bf16x8 a00 = *(const bf16x8*)(ap + k0);
    bf16x8 a01 = *(const bf16x8*)(ap + k0 + 32);
    bf16x8 a10 = *(const bf16x8*)(ap + 16*1024 + k0);
    bf16x8 a11 = *(const bf16x8*)(ap + 16*1024 + k0 + 32);
    bf16x8 a20 = *(const bf16x8*)(ap + 32*1024 + k0);
    bf16x8 a21 = *(const bf16x8*)(ap + 32*1024 + k0 + 32);
    bf16x8 a30 = *(const bf16x8*)(ap + 48*1024 + k0);
    bf16x8 a31 = *(const bf16x8*)(ap + 48*1024 + k0 + 32);
    bf16x8 b0 = pack8(w0,w1), b1 = pack8(w2,w3);
    acc0 = mfma16(a00,b0,acc0); acc1 = mfma16(a10,b0,acc1);
    acc2 = mfma16(a20,b0,acc2); acc3 = mfma16(a30,b0,acc3);
    acc0 = mfma16(a01,b1,acc0); acc1 = mfma16(a11,b1,acc1);
    acc2 = mfma16(a21,b1,acc2); acc3 = mfma16(a31,b1,acc3);
  }
  if(half==1){
    #pragma unroll
    for(int r=0;r<4;r++){
      red[cg][     lq*4+r][lm] = acc0[r];
      red[cg][16 + lq*4+r][lm] = acc1[r];
      red[cg][32 + lq*4+r][lm] = acc2[r];
      red[cg][48 + lq*4+r][lm] = acc3[r];
    }
  }
  __syncthreads();
  if(half==0){
    #pragma unroll
    for(int r=0;r<4;r++){
      acc0[r] += red[cg][     lq*4+r][lm];
      acc1[r] += red[cg][16 + lq*4+r][lm];
      acc2[r] += red[cg][32 + lq*4+r][lm];
      acc3[r] += red[cg][48 + lq*4+r][lm];
    }
    float bv=0.0f, wv=0.0f; int mv=-1;
    if(ncol < V){ bv = bias[ncol]; wv = wal[ncol]; mv = mem[ncol]; }
    #pragma unroll
    for(int qi=0; qi<4; qi++){
      #pragma unroll
      for(int r=0;r<4;r++){
        float v;
        if(qi==0) v = acc0[r]+bv; else if(qi==1) v = acc1[r]+bv;
        else if(qi==2) v = acc2[r]+bv; else v = acc3[r]+bv;
        int row = lq*4 + r + 16*qi;
        if(ncol < V) outf[(size_t)row*V + ncol] = v;
        // per-(row,col) contributions
        float dd = v*wv;
        float me = (mv==1) ? v : -1e30f;
        float se = (mv==1) ? 1.0f : 0.0f;
        float mg = (mv==0) ? v : -1e30f;
        float sg = (mv==0) ? 1.0f : 0.0f;
        // butterfly over the 16-lane group (same lq, lm=0..15)
        #pragma unroll
        for(int o=1;o<16;o<<=1){
          dd += __shfl_xor(dd,o);
          float m2=__shfl_xor(me,o), s2=__shfl_xor(se,o);
          float nm=fmaxf(me,m2); se = se*expf(me-nm) + s2*expf(m2-nm); me = nm;
          m2=__shfl_xor(mg,o); s2=__shfl_xor(sg,o);
          nm=fmaxf(mg,m2); sg = sg*expf(mg-nm) + s2*expf(m2-nm); mg = nm;
        }
        if(lm==0){
          sst[cg][row][0]=dd; sst[cg][row][1]=me; sst[cg][row][2]=se;
          sst[cg][row][3]=mg; sst[cg][row][4]=sg;
        }
      }
    }
  }
  __syncthreads();
  if(tid < 64){
    float dd=0.0f, me=-1e30f, se=0.0f, mg=-1e30f, sg=0.0f;
    #pragma unroll
    for(int g=0; g<4; g++){
      dd += sst[g][tid][0];
      float m2=sst[g][tid][1], s2=sst[g][tid][2];
      float nm=fmaxf(me,m2); se = se*expf(me-nm) + s2*expf(m2-nm); me = nm;
      m2=sst[g][tid][3]; s2=sst[g][tid][4];
      nm=fmaxf(mg,m2); sg = sg*expf(mg-nm) + s2*expf(m2-nm); mg = nm;
    }
    float* pp = pstat + ((size_t)tid*NBLK + blockIdx.x)*6;
    pp[0]=dd; pp[1]=me; pp[2]=se; pp[3]=mg; pp[4]=sg;
  }
}

// ---- 9: merge per-block stats partials -> stats[b][8] ----
__global__ void k_merge(const float* __restrict__ pstat, float* __restrict__ stats){
  int b = blockIdx.x, t = threadIdx.x;
  float dd=0.0f, me=-1e30f, se=0.0f, mg=-1e30f, sg=0.0f;
  for(int i=t; i<NBLK; i+=256){
    const float* pp = pstat + ((size_t)b*NBLK + i)*6;
    dd += pp[0];
    float m2=pp[1], s2=pp[2];
    float nm=fmaxf(me,m2); se = se*expf(me-nm) + s2*expf(m2-nm); me = nm;
    m2=pp[3]; s2=pp[4];
    nm=fmaxf(mg,m2); sg = sg*expf(mg-nm) + s2*expf(m2-nm); mg = nm;
  }
  #pragma unroll
  for(int o=32;o;o>>=1){
    dd += __shfl_xor(dd,o);
    float m2=__shfl_xor(me,o), s2=__shfl_xor(se,o);
    float nm=fmaxf(me,m2); se = se*expf(me-nm) + s2*expf(m2-nm); me = nm;
    m2=__shfl_xor(mg,o); s2=__shfl_xor(sg,o);
    nm=fmaxf(mg,m2); sg = sg*expf(mg-nm) + s2*expf(m2-nm); mg = nm;
  }
  __shared__ float sm[4][5];
  int wv = t>>6;
  if((t&63)==0){ sm[wv][0]=dd; sm[wv][1]=me; sm[wv][2]=se; sm[wv][3]=mg; sm[wv][4]=sg; }
  __syncthreads();
  if(t==0){
    float D=0, M=-1e30f, S=0, M2=-1e30f, S2=0;
    for(int i=0;i<4;i++){
      D += sm[i][0];
      float m = fmaxf(M, sm[i][1]); S  = S*expf(M-m)  + sm[i][2]*expf(sm[i][1]-m);  M = m;
      float n = fmaxf(M2,sm[i][3]); S2 = S2*expf(M2-n)+ sm[i][4]*expf(sm[i][3]-n); M2 = n;
    }
    stats[b*8+0]=D; stats[b*8+1]=M; stats[b*8+2]=M2; stats[b*8+3]=S; stats[b*8+4]=S2;
  }
}

// ---- 10: dual gated softmax in-place ----
__global__ void k_final(float* __restrict__ logits, const int* __restrict__ mem,
                        const float* __restrict__ stats, const float* __restrict__ balpha){
  int v = blockIdx.x*256 + threadIdx.x;
  int b = blockIdx.y;
  if(v >= V) return;
  float dot = stats[b*8+0], me = stats[b*8+1], mg = stats[b*8+2];
  float se = stats[b*8+3],  sg = stats[b*8+4];
  float g = sigm(dot + balpha[0]);
  float l = logits[(size_t)b*V + v];
  float o = (mem[v]==1) ? (expf(l-me)/se * g) : (expf(l-mg)/sg * (1.0f-g));
  logits[(size_t)b*V + v] = o;
}

extern "C" void kernel_launch(void* const* d_in, const int* in_sizes, int n_in,
                              void* d_out, int out_size, void* d_ws, size_t ws_size,
                              hipStream_t stream){
  const int*   istep   = (const int*)d_in[0];
  const int*   iemo    = (const int*)d_in[1];
  const float* lasth   = (const float*)d_in[2];
  const float* ictx    = (const float*)d_in[3];
  const float* enc     = (const float*)d_in[4];
  const int*   emem    = (const int*)d_in[5];
  const float* emb     = (const float*)d_in[6];
  const float* eemb    = (const float*)d_in[7];
  const float* W_read  = (const float*)d_in[8];
  const float* b_read  = (const float*)d_in[9];
  const float* W_write = (const float*)d_in[10];
  const float* b_write = (const float*)d_in[11];
  const float* W_ih    = (const float*)d_in[12];
  const float* W_hh    = (const float*)d_in[13];
  const float* b_ih    = (const float*)d_in[14];
  const float* b_hh    = (const float*)d_in[15];
  const float* W_concat= (const float*)d_in[16];
  const float* b_concat= (const float*)d_in[17];
  const float* W_out   = (const float*)d_in[18];
  const float* b_out   = (const float*)d_in[19];
  const float* W_alpha = (const float*)d_in[20];
  const float* b_alpha = (const float*)d_in[21];

  short* X_b  = (short*)d_ws;                           // 64x4096 bf16
  float* emog = (float*)((char*)d_ws + 524288);         // 64x1024
  float* gp   = emog + 65536;                           // 2x64x3072 (gi partials)
  float* gh   = gp + 393216;                            // 64x3072
  float* part = gh + 196608;                            // 64x32x1024
  float* ml   = part + 2097152;                         // 64x32x2
  float* stats= ml + 4096;                              // 512
  float* pstat= stats + 512;                            // 64x786x6
  short* hid_b= (short*)(pstat + 64*NBLK*6);            // 64x1024 bf16
  short* a2_b = hid_b + 65536;                          // 64x2048 bf16
  short* cc_b = a2_b + 131072;                          // 64x1024 bf16

  float* out0 = (float*)d_out;          // [64][V]
  float* hid  = out0 + (size_t)B*V;     // [64][1024] (output: hidden)
  float* memo = hid + 65536;            // [64][1024] (output: new_M_emo)
  float* ctxo = memo + 65536;           // [64][1024] (output: context)

  k_build<<<64,256,0,stream>>>(istep, lasth, ictx, emb, X_b);
  k_pre  <<<256,256,0,stream>>>(iemo, X_b, eemb, W_read, b_read, W_hh, emog, X_b, gh);
  k_gi   <<<dim3(192,2),256,0,stream>>>(X_b, W_ih, gp);
  k_gru  <<<64,256,0,stream>>>(gp, gh, b_ih, b_hh, lasth, hid, hid_b, a2_b);
  k_flash<<<576,256,0,stream>>>(enc, hid, part, ml, hid_b, W_write, b_write, emog, memo);
  k_ctxr <<<64,256,0,stream>>>(part, ml, ctxo, a2_b);
  k_cc   <<<64,256,0,stream>>>(a2_b, W_concat, b_concat, cc_b);
  k_out  <<<NBLK,512,0,stream>>>(cc_b, W_out, b_out, W_alpha, emem, out0, pstat);
  k_merge<<<64,256,0,stream>>>(pstat, stats);
  k_final<<<dim3(197,64),256,0,stream>>>(out0, emem, stats, b_alpha);
}

// Round 8
// 218.797 us; speedup vs baseline: 1.8959x; 1.0371x over previous
//
#include <hip/hip_runtime.h>
#include <hip/hip_bf16.h>
#include <math.h>

#define B 64
#define H 1024
#define SEQ 256
#define V 50257
#define NBLK 786   // ceil(V/64)

typedef float4 f4;
typedef __attribute__((ext_vector_type(4))) float f32x4;
typedef __attribute__((ext_vector_type(8))) short bf16x8;

__device__ inline float sigm(float x){ return 1.0f/(1.0f+expf(-x)); }
__device__ inline short f2bf(float x){
  __hip_bfloat16 h = __float2bfloat16(x);
  union { __hip_bfloat16 h; short s; } u; u.h = h; return u.s;
}
__device__ inline short2 cvt2(float x, float y){
  __hip_bfloat162 h = __float22bfloat162_rn(float2{x, y});
  union { __hip_bfloat162 h; short2 s; } u; u.h = h; return u.s;
}
__device__ inline bf16x8 pack8(f4 lo, f4 hi){
  union { bf16x8 v; short2 s[4]; } u;
  u.s[0]=cvt2(lo.x,lo.y); u.s[1]=cvt2(lo.z,lo.w);
  u.s[2]=cvt2(hi.x,hi.y); u.s[3]=cvt2(hi.z,hi.w);
  return u.v;
}
__device__ inline float wrsum(float v){
  #pragma unroll
  for(int o=32;o;o>>=1) v += __shfl_xor(v,o);
  return v;
}
__device__ inline float wrmax(float v){
  #pragma unroll
  for(int o=32;o;o>>=1) v = fmaxf(v,__shfl_xor(v,o));
  return v;
}
__device__ inline f32x4 mfma16(bf16x8 a, bf16x8 b, f32x4 c){
  return __builtin_amdgcn_mfma_f32_16x16x32_bf16(a,b,c,0,0,0);
}

// ---- 1: build X_b[:, :3072] = bf16[emb(iw) | lasth | ictx] ----
__global__ void k_build(const int* __restrict__ istep,
                        const float* __restrict__ lasth, const float* __restrict__ ictx,
                        const float* __restrict__ emb, short* __restrict__ X_b){
  int b = blockIdx.x; int h = threadIdx.x*4;
  int iw = istep[b];
  f4 lw = *(const f4*)(emb  + (size_t)iw*H + h);
  f4 hs = *(const f4*)(lasth + (size_t)b*H + h);
  f4 cv = *(const f4*)(ictx + (size_t)b*H + h);
  short* xb = X_b + (size_t)b*4096;
  *(short4*)(xb +        h) = make_short4(f2bf(lw.x),f2bf(lw.y),f2bf(lw.z),f2bf(lw.w));
  *(short4*)(xb + 1024 + h) = make_short4(f2bf(hs.x),f2bf(hs.y),f2bf(hs.z),f2bf(hs.w));
  *(short4*)(xb + 2048 + h) = make_short4(f2bf(cv.x),f2bf(cv.y),f2bf(cv.z),f2bf(cv.w));
}

// ---- 2: blocks 0..63: W_read gemm + sigmoid*eemb -> emog f32 + X_b[:,3072:] bf16
//         blocks 64..255: W_hh gemm (192 tiles) -> gh raw f32 ----
__launch_bounds__(256)
__global__ void k_pre(const int* __restrict__ iemo, const short* __restrict__ X_b,
                      const float* __restrict__ eemb,
                      const float* __restrict__ Wread, const float* __restrict__ bread,
                      const float* __restrict__ Whh,
                      float* __restrict__ emog, short* __restrict__ X_b_w,
                      float* __restrict__ gh){
  __shared__ float red[4][64][20];
  int tid = threadIdx.x;
  int w = tid>>6, l = tid&63, lm = l&15, lq = l>>4;
  f32x4 acc0={0,0,0,0}, acc1={0,0,0,0}, acc2={0,0,0,0}, acc3={0,0,0,0};
  int readmode = (blockIdx.x < 64);
  int tile = readmode ? blockIdx.x : (blockIdx.x - 64);
  int ncol = tile*16 + lm;
  const float* wp = readmode ? (Wread + (size_t)ncol*3072 + lq*8)
                             : (Whh   + (size_t)ncol*1024 + lq*8);
  const short* ap = readmode ? (X_b + lm*4096 + lq*8)
                             : (X_b + 1024 + lm*4096 + lq*8);
  int kbeg = readmode ? w*768 : w*256;
  int kend = readmode ? (kbeg + 768) : (kbeg + 256);
  for(int k0=kbeg; k0<kend; k0+=64){
    f4 w0 = *(const f4*)(wp + k0);
    f4 w1 = *(const f4*)(wp + k0 + 4);
    f4 w2 = *(const f4*)(wp + k0 + 32);
    f4 w3 = *(const f4*)(wp + k0 + 36);
    bf16x8 a00 = *(const bf16x8*)(ap + k0);
    bf16x8 a01 = *(const bf16x8*)(ap + k0 + 32);
    bf16x8 a10 = *(const bf16x8*)(ap + 16*4096 + k0);
    bf16x8 a11 = *(const bf16x8*)(ap + 16*4096 + k0 + 32);
    bf16x8 a20 = *(const bf16x8*)(ap + 32*4096 + k0);
    bf16x8 a21 = *(const bf16x8*)(ap + 32*4096 + k0 + 32);
    bf16x8 a30 = *(const bf16x8*)(ap + 48*4096 + k0);
    bf16x8 a31 = *(const bf16x8*)(ap + 48*4096 + k0 + 32);
    bf16x8 b0 = pack8(w0,w1), b1 = pack8(w2,w3);
    acc0 = mfma16(a00,b0,acc0); acc1 = mfma16(a10,b0,acc1);
    acc2 = mfma16(a20,b0,acc2); acc3 = mfma16(a30,b0,acc3);
    acc0 = mfma16(a01,b1,acc0); acc1 = mfma16(a11,b1,acc1);
    acc2 = mfma16(a21,b1,acc2); acc3 = mfma16(a31,b1,acc3);
  }
  #pragma unroll
  for(int r=0;r<4;r++){
    red[w][     lq*4+r][lm] = acc0[r];
    red[w][16 + lq*4+r][lm] = acc1[r];
    red[w][32 + lq*4+r][lm] = acc2[r];
    red[w][48 + lq*4+r][lm] = acc3[r];
  }
  __syncthreads();
  int m = tid>>2;
  if(readmode){
    int ie = iemo[m];
    #pragma unroll
    for(int j=0;j<4;j++){
      int c = (tid&3)*4 + j;
      float v = red[0][m][c]+red[1][m][c]+red[2][m][c]+red[3][m][c];
      int n = tile*16 + c;
      float s = sigm(v + bread[n]);
      float eg = s * eemb[(size_t)ie*1024 + n];
      emog[(size_t)m*1024 + n] = eg;
      X_b_w[(size_t)m*4096 + 3072 + n] = f2bf(eg);
    }
  } else {
    #pragma unroll
    for(int j=0;j<4;j++){
      int c = (tid&3)*4 + j;
      float v = red[0][m][c]+red[1][m][c]+red[2][m][c]+red[3][m][c];
      gh[(size_t)m*3072 + tile*16 + c] = v;
    }
  }
}

// ---- 3: gi partials = X @ W_ih^T, 2-way K-split (grid (192,2)) ----
__launch_bounds__(256)
__global__ void k_gi(const short* __restrict__ X_b, const float* __restrict__ Wih,
                     float* __restrict__ gp){
  __shared__ float red[4][64][20];
  int tid = threadIdx.x;
  int w = tid>>6, l = tid&63, lm = l&15, lq = l>>4;
  int half = blockIdx.y;
  int ncol = blockIdx.x*16 + lm;
  const float* wp = Wih + (size_t)ncol*4096 + lq*8;
  const short* ap = X_b + lm*4096 + lq*8;
  int kbeg = half*2048 + w*512, kend = kbeg + 512;
  f32x4 acc0={0,0,0,0}, acc1={0,0,0,0}, acc2={0,0,0,0}, acc3={0,0,0,0};
  for(int k0=kbeg; k0<kend; k0+=64){
    f4 w0 = *(const f4*)(wp + k0);
    f4 w1 = *(const f4*)(wp + k0 + 4);
    f4 w2 = *(const f4*)(wp + k0 + 32);
    f4 w3 = *(const f4*)(wp + k0 + 36);
    bf16x8 a00 = *(const bf16x8*)(ap + k0);
    bf16x8 a01 = *(const bf16x8*)(ap + k0 + 32);
    bf16x8 a10 = *(const bf16x8*)(ap + 16*4096 + k0);
    bf16x8 a11 = *(const bf16x8*)(ap + 16*4096 + k0 + 32);
    bf16x8 a20 = *(const bf16x8*)(ap + 32*4096 + k0);
    bf16x8 a21 = *(const bf16x8*)(ap + 32*4096 + k0 + 32);
    bf16x8 a30 = *(const bf16x8*)(ap + 48*4096 + k0);
    bf16x8 a31 = *(const bf16x8*)(ap + 48*4096 + k0 + 32);
    bf16x8 b0 = pack8(w0,w1), b1 = pack8(w2,w3);
    acc0 = mfma16(a00,b0,acc0); acc1 = mfma16(a10,b0,acc1);
    acc2 = mfma16(a20,b0,acc2); acc3 = mfma16(a30,b0,acc3);
    acc0 = mfma16(a01,b1,acc0); acc1 = mfma16(a11,b1,acc1);
    acc2 = mfma16(a21,b1,acc2); acc3 = mfma16(a31,b1,acc3);
  }
  #pragma unroll
  for(int r=0;r<4;r++){
    red[w][     lq*4+r][lm] = acc0[r];
    red[w][16 + lq*4+r][lm] = acc1[r];
    red[w][32 + lq*4+r][lm] = acc2[r];
    red[w][48 + lq*4+r][lm] = acc3[r];
  }
  __syncthreads();
  int m = tid>>2;
  #pragma unroll
  for(int j=0;j<4;j++){
    int c = (tid&3)*4 + j;
    float v = red[0][m][c]+red[1][m][c]+red[2][m][c]+red[3][m][c];
    gp[(size_t)(half*64+m)*3072 + blockIdx.x*16 + c] = v;
  }
}

// ---- 4: GRU elementwise (sums 2 gi partials + biases) ----
__global__ void k_gru(const float* __restrict__ gp, const float* __restrict__ gh,
                      const float* __restrict__ bih, const float* __restrict__ bhh,
                      const float* __restrict__ h0, float* __restrict__ hid,
                      short* __restrict__ hid_b, short* __restrict__ a2_b){
  int t = blockIdx.x*256 + threadIdx.x;   // 16384
  int b = t>>8, j = (t&255)*4;
  const float* gi0 = gp + (size_t)b*3072 + j;
  const float* gi1 = gp + (size_t)(64+b)*3072 + j;
  const float* ghb = gh + (size_t)b*3072 + j;
  f4 h0v = *(const f4*)(h0 + (size_t)b*1024 + j);
  f4 hres; short4 hb;
  #pragma unroll
  for(int c=0;c<4;c++){
    float r = sigm(gi0[c]      + gi1[c]      + bih[j+c]      + ghb[c]      + bhh[j+c]);
    float z = sigm(gi0[1024+c] + gi1[1024+c] + bih[1024+j+c] + ghb[1024+c] + bhh[1024+j+c]);
    float n = tanhf(gi0[2048+c] + gi1[2048+c] + bih[2048+j+c] + r*(ghb[2048+c] + bhh[2048+j+c]));
    float hv = ((const float*)&h0v)[c];
    float h = (1.0f - z)*n + z*hv;
    ((float*)&hres)[c] = h;
    ((short*)&hb)[c] = f2bf(h);
  }
  *(f4*)(hid + (size_t)b*1024 + j) = hres;
  *(short4*)(hid_b + (size_t)b*1024 + j) = hb;
  *(short4*)(a2_b + (size_t)b*2048 + j) = hb;
}

// ---- 5: blocks 0..511: flash attention chunks; blocks 512..575: W_write gemm ----
__launch_bounds__(256)
__global__ void k_flash(const float* __restrict__ enc, const float* __restrict__ hid,
                        float* __restrict__ part, float* __restrict__ ml,
                        const short* __restrict__ hid_b,
                        const float* __restrict__ Wwrite, const float* __restrict__ bwrite,
                        const float* __restrict__ emog, float* __restrict__ memo){
  __shared__ float red[4][64][20];
  int tid = threadIdx.x;
  int w = tid>>6, l = tid&63;
  if(blockIdx.x < 512){
    int b = blockIdx.x>>3, c = blockIdx.x&7;
    int chunk = c*4 + w;
    const float* hp = hid + (size_t)b*1024 + l*16;
    f4 q0 = *(const f4*)(hp), q1 = *(const f4*)(hp+4);
    f4 q2 = *(const f4*)(hp+8), q3 = *(const f4*)(hp+12);
    f4 cx0={0,0,0,0}, cx1={0,0,0,0}, cx2={0,0,0,0}, cx3={0,0,0,0};
    float mx = -1e30f, ls = 0.0f;
    int s0 = c*32 + w*8;
    for(int si=0; si<8; si++){
      const float* ep = enc + ((size_t)(s0+si)*64 + b)*1024 + l*16;
      f4 e0 = *(const f4*)(ep),   e1 = *(const f4*)(ep+4);
      f4 e2 = *(const f4*)(ep+8), e3 = *(const f4*)(ep+12);
      float d = e0.x*q0.x + e0.y*q0.y + e0.z*q0.z + e0.w*q0.w
              + e1.x*q1.x + e1.y*q1.y + e1.z*q1.z + e1.w*q1.w
              + e2.x*q2.x + e2.y*q2.y + e2.z*q2.z + e2.w*q2.w
              + e3.x*q3.x + e3.y*q3.y + e3.z*q3.z + e3.w*q3.w;
      d = wrsum(d);
      float mn = fmaxf(mx, d);
      float a = expf(mx - mn), p = expf(d - mn);
      ls = ls*a + p;
      cx0.x = cx0.x*a + p*e0.x; cx0.y = cx0.y*a + p*e0.y;
      cx0.z = cx0.z*a + p*e0.z; cx0.w = cx0.w*a + p*e0.w;
      cx1.x = cx1.x*a + p*e1.x; cx1.y = cx1.y*a + p*e1.y;
      cx1.z = cx1.z*a + p*e1.z; cx1.w = cx1.w*a + p*e1.w;
      cx2.x = cx2.x*a + p*e2.x; cx2.y = cx2.y*a + p*e2.y;
      cx2.z = cx2.z*a + p*e2.z; cx2.w = cx2.w*a + p*e2.w;
      cx3.x = cx3.x*a + p*e3.x; cx3.y = cx3.y*a + p*e3.y;
      cx3.z = cx3.z*a + p*e3.z; cx3.w = cx3.w*a + p*e3.w;
      mx = mn;
    }
    float* pp = part + ((size_t)b*32 + chunk)*1024 + l*16;
    *(f4*)(pp)    = cx0; *(f4*)(pp+4)  = cx1;
    *(f4*)(pp+8)  = cx2; *(f4*)(pp+12) = cx3;
    if(l==0){ ml[((size_t)b*32+chunk)*2] = mx; ml[((size_t)b*32+chunk)*2+1] = ls; }
  } else {
    int tile = blockIdx.x - 512;
    int lm = l&15, lq = l>>4;
    int ncol = tile*16 + lm;
    const float* wp = Wwrite + (size_t)ncol*1024 + lq*8;
    const short* ap = hid_b + lm*1024 + lq*8;
    int kbeg = w*256, kend = kbeg + 256;
    f32x4 acc0={0,0,0,0}, acc1={0,0,0,0}, acc2={0,0,0,0}, acc3={0,0,0,0};
    for(int k0=kbeg; k0<kend; k0+=64){
      f4 w0 = *(const f4*)(wp + k0);
      f4 w1 = *(const f4*)(wp + k0 + 4);
      f4 w2 = *(const f4*)(wp + k0 + 32);
      f4 w3 = *(const f4*)(wp + k0 + 36);
      bf16x8 a00 = *(const bf16x8*)(ap + k0);
      bf16x8 a01 = *(const bf16x8*)(ap + k0 + 32);
      bf16x8 a10 = *(const bf16x8*)(ap + 16*1024 + k0);
      bf16x8 a11 = *(const bf16x8*)(ap + 16*1024 + k0 + 32);
      bf16x8 a20 = *(const bf16x8*)(ap + 32*1024 + k0);
      bf16x8 a21 = *(const bf16x8*)(ap + 32*1024 + k0 + 32);
      bf16x8 a30 = *(const bf16x8*)(ap + 48*1024 + k0);
      bf16x8 a31 = *(const bf16x8*)(ap + 48*1024 + k0 + 32);
      bf16x8 b0 = pack8(w0,w1), b1 = pack8(w2,w3);
      acc0 = mfma16(a00,b0,acc0); acc1 = mfma16(a10,b0,acc1);
      acc2 = mfma16(a20,b0,acc2); acc3 = mfma16(a30,b0,acc3);
      acc0 = mfma16(a01,b1,acc0); acc1 = mfma16(a11,b1,acc1);
      acc2 = mfma16(a21,b1,acc2); acc3 = mfma16(a31,b1,acc3);
    }
    #pragma unroll
    for(int r=0;r<4;r++){
      red[w][     lq*4+r][lm] = acc0[r];
      red[w][16 + lq*4+r][lm] = acc1[r];
      red[w][32 + lq*4+r][lm] = acc2[r];
      red[w][48 + lq*4+r][lm] = acc3[r];
    }
    __syncthreads();
    int m = tid>>2;
    #pragma unroll
    for(int j=0;j<4;j++){
      int c = (tid&3)*4 + j;
      float v = red[0][m][c]+red[1][m][c]+red[2][m][c]+red[3][m][c];
      int n = tile*16 + c;
      memo[(size_t)m*1024 + n] = sigm(v + bwrite[n]) * emog[(size_t)m*1024 + n];
    }
  }
}

// ---- 6: merge 32 chunk partials -> context f32 (output) + a2_b[:, 1024:] bf16 ----
__global__ void k_ctxr(const float* __restrict__ part, const float* __restrict__ ml,
                       float* __restrict__ ctxo, short* __restrict__ a2_b){
  int b = blockIdx.x; int t = threadIdx.x;
  __shared__ float sscale[32];
  if(t < 64){
    float mc = (t<32) ? ml[((size_t)b*32+t)*2]   : -1e30f;
    float lc = (t<32) ? ml[((size_t)b*32+t)*2+1] : 0.0f;
    float M = wrmax(mc);
    float L = wrsum(lc * expf(mc - M));
    if(t<32) sscale[t] = expf(mc - M) / L;
  }
  __syncthreads();
  int h = t*4;
  f4 acc = {0,0,0,0};
  for(int c=0;c<32;c++){
    f4 p = *(const f4*)(part + ((size_t)b*32 + c)*1024 + h);
    float s = sscale[c];
    acc.x += s*p.x; acc.y += s*p.y; acc.z += s*p.z; acc.w += s*p.w;
  }
  *(f4*)(ctxo + (size_t)b*1024 + h) = acc;
  *(short4*)(a2_b + (size_t)b*2048 + 1024 + h) =
      make_short4(f2bf(acc.x),f2bf(acc.y),f2bf(acc.z),f2bf(acc.w));
}

// ---- 7: concat_out = tanh(a2 @ W_concat^T + b) -> cc_b bf16 ----
__launch_bounds__(256)
__global__ void k_cc(const short* __restrict__ a2_b, const float* __restrict__ Wc,
                     const float* __restrict__ bc, short* __restrict__ cc_b){
  __shared__ float red[4][64][20];
  int tid = threadIdx.x;
  int w = tid>>6, l = tid&63, lm = l&15, lq = l>>4;
  int ncol = blockIdx.x*16 + lm;
  const float* wp = Wc + (size_t)ncol*2048 + lq*8;
  const short* ap = a2_b + lm*2048 + lq*8;
  int kbeg = w*512, kend = kbeg + 512;
  f32x4 acc0={0,0,0,0}, acc1={0,0,0,0}, acc2={0,0,0,0}, acc3={0,0,0,0};
  for(int k0=kbeg; k0<kend; k0+=64){
    f4 w0 = *(const f4*)(wp + k0);
    f4 w1 = *(const f4*)(wp + k0 + 4);
    f4 w2 = *(const f4*)(wp + k0 + 32);
    f4 w3 = *(const f4*)(wp + k0 + 36);
    bf16x8 a00 = *(const bf16x8*)(ap + k0);
    bf16x8 a01 = *(const bf16x8*)(ap + k0 + 32);
    bf16x8 a10 = *(const bf16x8*)(ap + 16*2048 + k0);
    bf16x8 a11 = *(const bf16x8*)(ap + 16*2048 + k0 + 32);
    bf16x8 a20 = *(const bf16x8*)(ap + 32*2048 + k0);
    bf16x8 a21 = *(const bf16x8*)(ap + 32*2048 + k0 + 32);
    bf16x8 a30 = *(const bf16x8*)(ap + 48*2048 + k0);
    bf16x8 a31 = *(const bf16x8*)(ap + 48*2048 + k0 + 32);
    bf16x8 b0 = pack8(w0,w1), b1 = pack8(w2,w3);
    acc0 = mfma16(a00,b0,acc0); acc1 = mfma16(a10,b0,acc1);
    acc2 = mfma16(a20,b0,acc2); acc3 = mfma16(a30,b0,acc3);
    acc0 = mfma16(a01,b1,acc0); acc1 = mfma16(a11,b1,acc1);
    acc2 = mfma16(a21,b1,acc2); acc3 = mfma16(a31,b1,acc3);
  }
  #pragma unroll
  for(int r=0;r<4;r++){
    red[w][     lq*4+r][lm] = acc0[r];
    red[w][16 + lq*4+r][lm] = acc1[r];
    red[w][32 + lq*4+r][lm] = acc2[r];
    red[w][48 + lq*4+r][lm] = acc3[r];
  }
  __syncthreads();
  int m = tid>>2;
  #pragma unroll
  for(int j=0;j<4;j++){
    int c = (tid&3)*4 + j;
    float v = red[0][m][c]+red[1][m][c]+red[2][m][c]+red[3][m][c];
    int n = blockIdx.x*16 + c;
    cc_b[(size_t)m*1024 + n] = f2bf(tanhf(v + bc[n]));
  }
}

// ---- 8: logits = cc @ W_out^T + b_out. LDS-tiled W staging (coalesced, dbuf),
//         full K per wave, fused per-block row stats ----
__launch_bounds__(256)
__global__ void k_out(const short* __restrict__ A, const float* __restrict__ Wm,
                      const float* __restrict__ bias, const float* __restrict__ wal,
                      const int* __restrict__ mem,
                      float* __restrict__ outf, float* __restrict__ pstat){
  __shared__ float wt[2][64][132];   // 67.6 KB: K-step 128, pad +4 (2-way read conflict)
  __shared__ float sst[4][64][6];    // per col-group per-row stats
  int tid = threadIdx.x;
  int w = tid>>6, l = tid&63;
  int lm = l&15, lq = l>>4;
  int n0 = blockIdx.x*64;
  int ncol = n0 + w*16 + lm;
  int fr = w*16 + lm;                    // this lane's W row within the LDS tile
  const short* ap = A + lm*1024 + lq*8;
  f32x4 acc0={0,0,0,0}, acc1={0,0,0,0}, acc2={0,0,0,0}, acc3={0,0,0,0};

  // stage step 0 (coalesced: 32 consecutive threads cover one row's 512 B)
  {
    #pragma unroll
    for(int c=0;c<8;c++){
      int idx = c*256 + tid;
      int row = idx>>5, kc = idx&31;
      int srow = n0 + row; if(srow > V-1) srow = V-1;
      f4 v = *(const f4*)(Wm + (size_t)srow*1024 + kc*4);
      *(f4*)(&wt[0][row][kc*4]) = v;
    }
  }
  __syncthreads();

  int buf = 0;
  for(int step=0; step<8; step++){
    if(step < 7){
      int k0n = (step+1)*128;
      #pragma unroll
      for(int c=0;c<8;c++){
        int idx = c*256 + tid;
        int row = idx>>5, kc = idx&31;
        int srow = n0 + row; if(srow > V-1) srow = V-1;
        f4 v = *(const f4*)(Wm + (size_t)srow*1024 + k0n + kc*4);
        *(f4*)(&wt[buf^1][row][kc*4]) = v;
      }
    }
    int kg = step*128;
    #pragma unroll
    for(int kk=0; kk<128; kk+=64){
      f4 lo0 = *(const f4*)(&wt[buf][fr][kk + lq*8]);
      f4 hi0 = *(const f4*)(&wt[buf][fr][kk + lq*8 + 4]);
      f4 lo1 = *(const f4*)(&wt[buf][fr][kk + 32 + lq*8]);
      f4 hi1 = *(const f4*)(&wt[buf][fr][kk + 36 + lq*8]);
      bf16x8 b0 = pack8(lo0,hi0), b1 = pack8(lo1,hi1);
      int ka = kg + kk;
      bf16x8 a00 = *(const bf16x8*)(ap + ka);
      bf16x8 a01 = *(const bf16x8*)(ap + ka + 32);
      bf16x8 a10 = *(const bf16x8*)(ap + 16*1024 + ka);
      bf16x8 a11 = *(const bf16x8*)(ap + 16*1024 + ka + 32);
      bf16x8 a20 = *(const bf16x8*)(ap + 32*1024 + ka);
      bf16x8 a21 = *(const bf16x8*)(ap + 32*1024 + ka + 32);
      bf16x8 a30 = *(const bf16x8*)(ap + 48*1024 + ka);
      bf16x8 a31 = *(const bf16x8*)(ap + 48*1024 + ka + 32);
      acc0 = mfma16(a00,b0,acc0); acc1 = mfma16(a10,b0,acc1);
      acc2 = mfma16(a20,b0,acc2); acc3 = mfma16(a30,b0,acc3);
      acc0 = mfma16(a01,b1,acc0); acc1 = mfma16(a11,b1,acc1);
      acc2 = mfma16(a21,b1,acc2); acc3 = mfma16(a31,b1,acc3);
    }
    __syncthreads();
    buf ^= 1;
  }

  // epilogue: bias + store + fused row stats (16-lane butterfly per row)
  float bv=0.0f, wv=0.0f; int mv=-1;
  if(ncol < V){ bv = bias[ncol]; wv = wal[ncol]; mv = mem[ncol]; }
  #pragma unroll
  for(int qi=0; qi<4; qi++){
    #pragma unroll
    for(int r=0;r<4;r++){
      float v;
      if(qi==0) v = acc0[r]+bv; else if(qi==1) v = acc1[r]+bv;
      else if(qi==2) v = acc2[r]+bv; else v = acc3[r]+bv;
      int row = lq*4 + r + 16*qi;
      if(ncol < V) outf[(size_t)row*V + ncol] = v;
      float dd = v*wv;
      float me = (mv==1) ? v : -1e30f;
      float se = (mv==1) ? 1.0f : 0.0f;
      float mg = (mv==0) ? v : -1e30f;
      float sg = (mv==0) ? 1.0f : 0.0f;
      #pragma unroll
      for(int o=1;o<16;o<<=1){
        dd += __shfl_xor(dd,o);
        float m2=__shfl_xor(me,o), s2=__shfl_xor(se,o);
        float nm=fmaxf(me,m2); se = se*expf(me-nm) + s2*expf(m2-nm); me = nm;
        m2=__shfl_xor(mg,o); s2=__shfl_xor(sg,o);
        nm=fmaxf(mg,m2); sg = sg*expf(mg-nm) + s2*expf(m2-nm); mg = nm;
      }
      if(lm==0){
        sst[w][row][0]=dd; sst[w][row][1]=me; sst[w][row][2]=se;
        sst[w][row][3]=mg; sst[w][row][4]=sg;
      }
    }
  }
  __syncthreads();
  if(tid < 64){
    float dd=0.0f, me=-1e30f, se=0.0f, mg=-1e30f, sg=0.0f;
    #pragma unroll
    for(int g=0; g<4; g++){
      dd += sst[g][tid][0];
      float m2=sst[g][tid][1], s2=sst[g][tid][2];
      float nm=fmaxf(me,m2); se = se*expf(me-nm) + s2*expf(m2-nm); me = nm;
      m2=sst[g][tid][3]; s2=sst[g][tid][4];
      nm=fmaxf(mg,m2); sg = sg*expf(mg-nm) + s2*expf(m2-nm); mg = nm;
    }
    float* pp = pstat + ((size_t)tid*NBLK + blockIdx.x)*6;
    pp[0]=dd; pp[1]=me; pp[2]=se; pp[3]=mg; pp[4]=sg;
  }
}

// ---- 9: merge per-block stats partials -> stats[b][8] ----
__global__ void k_merge(const float* __restrict__ pstat, float* __restrict__ stats){
  int b = blockIdx.x, t = threadIdx.x;
  float dd=0.0f, me=-1e30f, se=0.0f, mg=-1e30f, sg=0.0f;
  for(int i=t; i<NBLK; i+=256){
    const float* pp = pstat + ((size_t)b*NBLK + i)*6;
    dd += pp[0];
    float m2=pp[1], s2=pp[2];
    float nm=fmaxf(me,m2); se = se*expf(me-nm) + s2*expf(m2-nm); me = nm;
    m2=pp[3]; s2=pp[4];
    nm=fmaxf(mg,m2); sg = sg*expf(mg-nm) + s2*expf(m2-nm); mg = nm;
  }
  #pragma unroll
  for(int o=32;o;o>>=1){
    dd += __shfl_xor(dd,o);
    float m2=__shfl_xor(me,o), s2=__shfl_xor(se,o);
    float nm=fmaxf(me,m2); se = se*expf(me-nm) + s2*expf(m2-nm); me = nm;
    m2=__shfl_xor(mg,o); s2=__shfl_xor(sg,o);
    nm=fmaxf(mg,m2); sg = sg*expf(mg-nm) + s2*expf(m2-nm); mg = nm;
  }
  __shared__ float sm[4][5];
  int wv = t>>6;
  if((t&63)==0){ sm[wv][0]=dd; sm[wv][1]=me; sm[wv][2]=se; sm[wv][3]=mg; sm[wv][4]=sg; }
  __syncthreads();
  if(t==0){
    float D=0, M=-1e30f, S=0, M2=-1e30f, S2=0;
    for(int i=0;i<4;i++){
      D += sm[i][0];
      float m = fmaxf(M, sm[i][1]); S  = S*expf(M-m)  + sm[i][2]*expf(sm[i][1]-m);  M = m;
      float n = fmaxf(M2,sm[i][3]); S2 = S2*expf(M2-n)+ sm[i][4]*expf(sm[i][3]-n); M2 = n;
    }
    stats[b*8+0]=D; stats[b*8+1]=M; stats[b*8+2]=M2; stats[b*8+3]=S; stats[b*8+4]=S2;
  }
}

// ---- 10: dual gated softmax in-place ----
__global__ void k_final(float* __restrict__ logits, const int* __restrict__ mem,
                        const float* __restrict__ stats, const float* __restrict__ balpha){
  int v = blockIdx.x*256 + threadIdx.x;
  int b = blockIdx.y;
  if(v >= V) return;
  float dot = stats[b*8+0], me = stats[b*8+1], mg = stats[b*8+2];
  float se = stats[b*8+3],  sg = stats[b*8+4];
  float g = sigm(dot + balpha[0]);
  float l = logits[(size_t)b*V + v];
  float o = (mem[v]==1) ? (expf(l-me)/se * g) : (expf(l-mg)/sg * (1.0f-g));
  logits[(size_t)b*V + v] = o;
}

extern "C" void kernel_launch(void* const* d_in, const int* in_sizes, int n_in,
                              void* d_out, int out_size, void* d_ws, size_t ws_size,
                              hipStream_t stream){
  const int*   istep   = (const int*)d_in[0];
  const int*   iemo    = (const int*)d_in[1];
  const float* lasth   = (const float*)d_in[2];
  const float* ictx    = (const float*)d_in[3];
  const float* enc     = (const float*)d_in[4];
  const int*   emem    = (const int*)d_in[5];
  const float* emb     = (const float*)d_in[6];
  const float* eemb    = (const float*)d_in[7];
  const float* W_read  = (const float*)d_in[8];
  const float* b_read  = (const float*)d_in[9];
  const float* W_write = (const float*)d_in[10];
  const float* b_write = (const float*)d_in[11];
  const float* W_ih    = (const float*)d_in[12];
  const float* W_hh    = (const float*)d_in[13];
  const float* b_ih    = (const float*)d_in[14];
  const float* b_hh    = (const float*)d_in[15];
  const float* W_concat= (const float*)d_in[16];
  const float* b_concat= (const float*)d_in[17];
  const float* W_out   = (const float*)d_in[18];
  const float* b_out   = (const float*)d_in[19];
  const float* W_alpha = (const float*)d_in[20];
  const float* b_alpha = (const float*)d_in[21];

  short* X_b  = (short*)d_ws;                           // 64x4096 bf16
  float* emog = (float*)((char*)d_ws + 524288);         // 64x1024
  float* gp   = emog + 65536;                           // 2x64x3072 (gi partials)
  float* gh   = gp + 393216;                            // 64x3072
  float* part = gh + 196608;                            // 64x32x1024
  float* ml   = part + 2097152;                         // 64x32x2
  float* stats= ml + 4096;                              // 512
  float* pstat= stats + 512;                            // 64x786x6
  short* hid_b= (short*)(pstat + 64*NBLK*6);            // 64x1024 bf16
  short* a2_b = hid_b + 65536;                          // 64x2048 bf16
  short* cc_b = a2_b + 131072;                          // 64x1024 bf16

  float* out0 = (float*)d_out;          // [64][V]
  float* hid  = out0 + (size_t)B*V;     // [64][1024] (output: hidden)
  float* memo = hid + 65536;            // [64][1024] (output: new_M_emo)
  float* ctxo = memo + 65536;           // [64][1024] (output: context)

  k_build<<<64,256,0,stream>>>(istep, lasth, ictx, emb, X_b);
  k_pre  <<<256,256,0,stream>>>(iemo, X_b, eemb, W_read, b_read, W_hh, emog, X_b, gh);
  k_gi   <<<dim3(192,2),256,0,stream>>>(X_b, W_ih, gp);
  k_gru  <<<64,256,0,stream>>>(gp, gh, b_ih, b_hh, lasth, hid, hid_b, a2_b);
  k_flash<<<576,256,0,stream>>>(enc, hid, part, ml, hid_b, W_write, b_write, emog, memo);
  k_ctxr <<<64,256,0,stream>>>(part, ml, ctxo, a2_b);
  k_cc   <<<64,256,0,stream>>>(a2_b, W_concat, b_concat, cc_b);
  k_out  <<<NBLK,256,0,stream>>>(cc_b, W_out, b_out, W_alpha, emem, out0, pstat);
  k_merge<<<64,256,0,stream>>>(pstat, stats);
  k_final<<<dim3(197,64),256,0,stream>>>(out0, emem, stats, b_alpha);
}